// Round 15
// baseline (674.664 us; speedup 1.0000x reference)
//
#include <hip/hip_runtime.h>
#include <hip/hip_bf16.h>

#define TPB 256

typedef __attribute__((ext_vector_type(8))) short short8;
typedef __attribute__((ext_vector_type(4))) float f32x4;

__device__ __forceinline__ unsigned short f2bf(float x) {
    union { float f; unsigned int u; } c; c.f = x;
    unsigned int u = c.u;
    unsigned int r = (u + 0x7fffu + ((u >> 16) & 1u)) >> 16;
    return (unsigned short)r;
}

// ---- in-block GN stats (C=64, G=32): X image base -> sM[32], sR[32] ----
// thread t: ch = t>>2, seg = t&3; 4-seg + channel-pair reduce via LDS.
#define IN_STATS(Xp, HW)                                                        \
    {                                                                           \
        int ch_ = t >> 2, sg_ = t & 3;                                          \
        float s_ = 0.f, s2_ = 0.f;                                              \
        for (int i_ = sg_; i_ < (HW); i_ += 4) {                                \
            float v_ = (Xp)[(size_t)ch_ * (HW) + i_];                           \
            s_ += v_; s2_ += v_ * v_;                                           \
        }                                                                       \
        rsum[t] = s_; rssq[t] = s2_;                                            \
        __syncthreads();                                                        \
        if (t < 32) {                                                           \
            float S = 0.f, S2 = 0.f;                                            \
            _Pragma("unroll")                                                   \
            for (int k_ = 0; k_ < 8; k_++) {                                    \
                int tt_ = (2 * t + (k_ & 1)) * 4 + (k_ >> 1);                   \
                S += rsum[tt_]; S2 += rssq[tt_];                                \
            }                                                                   \
            float mu_ = S / (2.f * (HW));                                       \
            sM[t] = mu_;                                                        \
            sR[t] = rsqrtf(S2 / (2.f * (HW)) - mu_ * mu_ + 1e-5f);              \
        }                                                                       \
        __syncthreads();                                                        \
    }

// ======================= conv1 (unchanged) ===================================

__global__ void conv1_k(const float* __restrict__ x, const float* __restrict__ w,
                        const float* __restrict__ b, float* __restrict__ out) {
    int idx = blockIdx.x * TPB + threadIdx.x;
    const int total = 512 * 64 * 26 * 26;
    if (idx >= total) return;
    int ox = idx % 26; int t = idx / 26;
    int oy = t % 26;   t /= 26;
    int co = t % 64;   int n = t / 64;
    const float* xp = x + (size_t)n * 784 + oy * 28 + ox;
    const float* wp = w + co * 9;
    float s = b[co];
#pragma unroll
    for (int ky = 0; ky < 3; ky++)
#pragma unroll
        for (int kx = 0; kx < 3; kx++)
            s += xp[ky * 28 + kx] * wp[ky * 3 + kx];
    out[idx] = s;
}

// ======================= combined weight prep ================================
// 6 conv3 tables + 2 conv1 tables into one contiguous region.
// conv3 layout [t:9][ks:2][nt:4][lane:64][8]; conv1 [ks:2][nt:4][lane:64][8].

__global__ void wsplit_all_k(const float* __restrict__ w0, const float* __restrict__ w1,
                             const float* __restrict__ w2, const float* __restrict__ w3,
                             const float* __restrict__ w4, const float* __restrict__ w5,
                             const float* __restrict__ d0, const float* __restrict__ d1,
                             unsigned short* __restrict__ dst) {
    const int WBS = 9 * 2 * 4 * 64 * 8, WBS1 = 2 * 4 * 64 * 8;
    int i = blockIdx.x * TPB + threadIdx.x;
    if (i < 6 * WBS) {
        int tbl = i / WBS; int r = i - tbl * WBS;
        const float* w = (tbl == 0) ? w0 : (tbl == 1) ? w1 : (tbl == 2) ? w2
                       : (tbl == 3) ? w3 : (tbl == 4) ? w4 : w5;
        int j = r & 7, l = (r >> 3) & 63, nt = (r >> 9) & 3, ks = (r >> 11) & 1, tt = r >> 12;
        int co = nt * 16 + (l & 15);
        int ci = ks * 32 + (l >> 4) * 8 + j;
        dst[i] = f2bf(w[(co * 64 + ci) * 9 + tt]);
    } else {
        int r = i - 6 * WBS;
        if (r >= 2 * WBS1) return;
        int tbl = r / WBS1; r -= tbl * WBS1;
        const float* w = tbl ? d1 : d0;
        int j = r & 7, l = (r >> 3) & 63, nt = (r >> 9) & 3, ks = (r >> 11) & 1;
        int co = nt * 16 + (l & 15);
        int ci = ks * 32 + (l >> 4) * 8 + j;
        dst[6 * WBS + tbl * WBS1 + r] = f2bf(w[co * 64 + ci]);
    }
}

// ======================= stride-2 MFMA conv (+self GN, +1x1 skip) ============

__global__ __launch_bounds__(256, 2)
void conv_s2_mfma_k(const float* __restrict__ in,
                    const unsigned short* __restrict__ bhT,
                    const unsigned short* __restrict__ dwT,
                    float* __restrict__ out, float* __restrict__ skipout,
                    const float* __restrict__ gnw, const float* __restrict__ gnb,
                    int H, int W, int OH, int OW, int TX, int TY) {
    __shared__ unsigned short hp[256 * 72];
    __shared__ float rsum[256], rssq[256], sM[32], sR[32];

    int b = blockIdx.x;
    int tx = b % TX; b /= TX;
    int ty = b % TY; int n = b / TY;
    int oy0 = ty * 7, ox0 = tx * 7;

    const int t = threadIdx.x;
    const int lane = t & 63, nt = t >> 6;
    const int colL = lane & 15, q = lane >> 4;
    const int co = nt * 16 + colL;
    const int kq0 = q * 8;

    short8 wr[18], dr[2];
#pragma unroll
    for (int i = 0; i < 18; i++) wr[i] = ((const short8*)bhT)[(i * 4 + nt) * 64 + lane];
    dr[0] = ((const short8*)dwT)[(0 * 4 + nt) * 64 + lane];
    dr[1] = ((const short8*)dwT)[(1 * 4 + nt) * 64 + lane];

    for (int i = t; i < 256 * 72 / 2; i += 256) ((unsigned int*)hp)[i] = 0u;

    const float* ip = in + (size_t)n * 64 * H * W;
    IN_STATS(ip, H * W)

    // ---- stage 15x16 phase-split tile with fused GN+ReLU ----
    for (int i = t; i < 64 * 240; i += 256) {
        int ch = i / 240; int rc = i - ch * 240;
        int r = rc >> 4, c = rc & 15;
        int iy = 2 * oy0 - 1 + r;
        int ix = (c < 8) ? (2 * ox0 + 2 * c) : (2 * ox0 - 1 + 2 * (c - 8));
        if ((unsigned)iy < (unsigned)H && (unsigned)ix < (unsigned)W) {
            float m = sM[ch >> 1], rs = sR[ch >> 1];
            float raw = ip[(size_t)ch * H * W + iy * W + ix];
            float v = fmaxf((raw - m) * rs * gnw[ch] + gnb[ch], 0.f);
            hp[(r * 16 + c) * 72 + ch] = f2bf(v);
        }
    }
    __syncthreads();

    int bs0, bs1, bs2, bs3;
    {
#define BSLOT(dst, mm)                                                          \
        {                                                                       \
            int p_ = (mm) * 16 + colL;                                          \
            int oy_ = p_ >> 3, ox_ = p_ & 7;                                    \
            dst = (ox_ < 7 && oy_ < 7) ? ((2 * oy_) * 16 + ox_) : 0;            \
        }
        BSLOT(bs0, 0) BSLOT(bs1, 1) BSLOT(bs2, 2) BSLOT(bs3, 3)
#undef BSLOT
    }

    f32x4 a0, a1, a2, a3, k0, k1, k2, k3;
    a0 = (f32x4){0.f, 0.f, 0.f, 0.f}; a1 = a0; a2 = a0; a3 = a0;
    k0 = a0; k1 = a0; k2 = a0; k3 = a0;

#pragma unroll
    for (int t9 = 0; t9 < 9; t9++) {
        const int kx = t9 % 3;
        const int toff = (t9 / 3) * 16 + (kx == 0 ? 8 : (kx == 1 ? 0 : 9));
#pragma unroll
        for (int ks = 0; ks < 2; ks++) {
            short8 vb = wr[t9 * 2 + ks];
            int kq = ks * 32 + kq0;
#define TAP(areg, bs)                                                           \
            {                                                                   \
                short8 av = *(const short8*)(hp + ((bs) + toff) * 72 + kq);     \
                areg = __builtin_amdgcn_mfma_f32_16x16x32_bf16(av, vb, areg, 0, 0, 0); \
            }
            TAP(a0, bs0) TAP(a1, bs1) TAP(a2, bs2) TAP(a3, bs3)
#undef TAP
        }
    }
#pragma unroll
    for (int ks = 0; ks < 2; ks++) {
        short8 vb = dr[ks];
        int kq = ks * 32 + kq0;
#define TAP(areg, bs)                                                           \
        {                                                                       \
            short8 av = *(const short8*)(hp + ((bs) + 16) * 72 + kq);           \
            areg = __builtin_amdgcn_mfma_f32_16x16x32_bf16(av, vb, areg, 0, 0, 0); \
        }
        TAP(k0, bs0) TAP(k1, bs1) TAP(k2, bs2) TAP(k3, bs3)
#undef TAP
    }

#define WB(areg, kreg, mm)                                                      \
    _Pragma("unroll")                                                           \
    for (int j = 0; j < 4; j++) {                                               \
        int p_ = (mm) * 16 + q * 4 + j;                                         \
        int oy_ = p_ >> 3, ox_ = p_ & 7;                                        \
        if (ox_ < 7 && oy_ < 7 && oy0 + oy_ < OH && ox0 + ox_ < OW) {           \
            size_t idx = (((size_t)n * 64 + co) * OH + oy0 + oy_) * OW + ox0 + ox_; \
            out[idx] = areg[j];                                                 \
            skipout[idx] = kreg[j];                                             \
        }                                                                       \
    }
    WB(a0, k0, 0) WB(a1, k1, 1) WB(a2, k2, 2) WB(a3, k3, 3)
#undef WB
}

// ======================= 13x13 MFMA conv (r1_c2, self GN) ====================

__global__ __launch_bounds__(256, 2)
void conv13_mfma_k(const float* __restrict__ in, const unsigned short* __restrict__ bhT,
                   float* __restrict__ io,
                   const float* __restrict__ gnw, const float* __restrict__ gnb) {
    __shared__ unsigned short hp[256 * 72];
    __shared__ float rsum[256], rssq[256], sM[32], sR[32];
    const int t = threadIdx.x;
    const int n = blockIdx.x;
    const int lane = t & 63;
    const int nt = t >> 6;
    const int colL = lane & 15, q = lane >> 4;
    const int co = nt * 16 + colL;
    const int kq0 = q * 8;

    short8 wr[18];
#pragma unroll
    for (int i = 0; i < 18; i++) wr[i] = ((const short8*)bhT)[(i * 4 + nt) * 64 + lane];

    for (int i = t; i < 256 * 72 / 2; i += 256) ((unsigned int*)hp)[i] = 0u;

    const float* ip = in + (size_t)n * 64 * 169;
    IN_STATS(ip, 169)

    for (int i = t; i < 64 * 169; i += 256) {
        int ch = i / 169, p = i - ch * 169;
        int y = p / 13, x = p - y * 13;
        float m = sM[ch >> 1], rs = sR[ch >> 1];
        float v = fmaxf((ip[i] - m) * rs * gnw[ch] + gnb[ch], 0.f);
        hp[((y + 1) * 16 + (x + 1)) * 72 + ch] = f2bf(v);
    }
    __syncthreads();

    int hb[11];
#pragma unroll
    for (int m = 0; m < 11; m++) {
        int p = m * 16 + colL;
        int y = p / 13, x = p - y * 13;
        hb[m] = (y + 1) * 16 + (x + 1);
    }
    f32x4 acc[11];
#pragma unroll
    for (int m = 0; m < 11; m++) acc[m] = (f32x4){0.f, 0.f, 0.f, 0.f};

#pragma unroll
    for (int t9 = 0; t9 < 9; t9++) {
        const int toff = (t9 / 3) * 16 + (t9 % 3) - 17;
#pragma unroll
        for (int ks = 0; ks < 2; ks++) {
            short8 vb = wr[t9 * 2 + ks];
            int kq = ks * 32 + kq0;
#pragma unroll
            for (int m = 0; m < 11; m++) {
                short8 a_ = *(const short8*)(hp + (hb[m] + toff) * 72 + kq);
                acc[m] = __builtin_amdgcn_mfma_f32_16x16x32_bf16(a_, vb, acc[m], 0, 0, 0);
            }
        }
    }

    float* op = io + (size_t)n * 64 * 169 + (size_t)co * 169;
#pragma unroll
    for (int m = 0; m < 11; m++) {
        int p0 = m * 16 + q * 4;
#pragma unroll
        for (int j = 0; j < 4; j++) {
            int p = p0 + j;
            if (p < 169) op[p] += acc[m][j];
        }
    }
}

// ======================= ODE MFMA mega-kernel ================================

#define HP_PITCH 72
#define HP_PLANE (100 * HP_PITCH)

#define PVALID(p) ((((p) & 7) < 7) && (((p) >> 3) < 7))
#define PSLOT(p)  (((((p) >> 3) + 1) * 10) + (((p) & 7) + 1))

#define CONV_TAP(areg, hbase)                                                   \
    {                                                                           \
        short8 a_ = *(const short8*)(hp + ((hbase) + toff) * HP_PITCH + kq);    \
        areg = __builtin_amdgcn_mfma_f32_16x16x32_bf16(a_, vb, areg, 0, 0, 0);  \
    }

#define CONV_MFMA(hpsrc, wreg)                                                  \
    a0 = (f32x4){0.f, 0.f, 0.f, 0.f}; a1 = a0; a2 = a0; a3 = a0;                \
    {                                                                           \
        const unsigned short* hp = (hpsrc);                                     \
        _Pragma("unroll")                                                       \
        for (int t9 = 0; t9 < 9; t9++) {                                        \
            const int toff = (t9 / 3) * 10 + (t9 % 3) - 11;                     \
            _Pragma("unroll")                                                   \
            for (int ks = 0; ks < 2; ks++) {                                    \
                short8 vb = wreg[t9 * 2 + ks];                                  \
                int kq = ks * 32 + kq0;                                         \
                CONV_TAP(a0, h0)                                                \
                CONV_TAP(a1, h1)                                                \
                CONV_TAP(a2, h2)                                                \
                CONV_TAP(a3, h3)                                                \
            }                                                                   \
        }                                                                       \
    }

#define CONV_MFMA_G(hpsrc, bhT)                                                 \
    a0 = (f32x4){0.f, 0.f, 0.f, 0.f}; a1 = a0; a2 = a0; a3 = a0;                \
    {                                                                           \
        const unsigned short* hp = (hpsrc);                                     \
        const short8* bh_ = (const short8*)(bhT);                               \
        _Pragma("unroll")                                                       \
        for (int t9 = 0; t9 < 9; t9++) {                                        \
            const int toff = (t9 / 3) * 10 + (t9 % 3) - 11;                     \
            _Pragma("unroll")                                                   \
            for (int ks = 0; ks < 2; ks++) {                                    \
                short8 vb = bh_[((t9 * 2 + ks) * 4 + nt) * 64 + lane];          \
                int kq = ks * 32 + kq0;                                         \
                CONV_TAP(a0, h0)                                                \
                CONV_TAP(a1, h1)                                                \
                CONV_TAP(a2, h2)                                                \
                CONV_TAP(a3, h3)                                                \
            }                                                                   \
        }                                                                       \
    }

#define GN_ACCUM(areg, mm)                                                      \
    _Pragma("unroll")                                                           \
    for (int j = 0; j < 4; j++) {                                               \
        int p_ = (mm) * 16 + q * 4 + j;                                         \
        if (PVALID(p_)) { float x_ = areg[j]; s += x_; s2 += x_ * x_; }         \
    }

#define GN_STORE(dst, areg, mm)                                                 \
    _Pragma("unroll")                                                           \
    for (int j = 0; j < 4; j++) {                                               \
        int p_ = (mm) * 16 + q * 4 + j;                                         \
        if (PVALID(p_)) {                                                       \
            float y_ = fmaxf(areg[j] * sc + sh, 0.f);                           \
            (dst)[PSLOT(p_) * HP_PITCH + co] = f2bf(y_);                        \
        }                                                                       \
    }

#define RK4_REG(areg, zm, zam, um)                                              \
    {                                                                           \
        f32x4 kv = areg + um;                                                   \
        zam = (e == 0) ? (zm + ck * kv) : (zam + ck * kv);                      \
        if (e < 3) um = zm + cu * kv;                                           \
    }

__global__ __launch_bounds__(256, 2)
void ode_mfma_k(const float* __restrict__ u7raw, const float* __restrict__ z7,
                const float* __restrict__ pgw, const float* __restrict__ pgb,
                const unsigned short* __restrict__ wr2h,
                const unsigned short* __restrict__ wb1h,
                const unsigned short* __restrict__ wb2h,
                const float* __restrict__ g1w, const float* __restrict__ g1b,
                const float* __restrict__ g2w, const float* __restrict__ g2b,
                const float* __restrict__ fgw, const float* __restrict__ fgb,
                const float* __restrict__ fcw, const float* __restrict__ fcb,
                float* __restrict__ out) {
    __shared__ unsigned short hp1[HP_PLANE], hp2[HP_PLANE];
    __shared__ float rsum[256], rssq[256], sM[32], sR[32];
    __shared__ float pooled[64];

    const int t = threadIdx.x;
    const int n = blockIdx.x;
    const int lane = t & 63;
    const int nt = t >> 6;
    const int colL = lane & 15, q = lane >> 4;
    const int co = nt * 16 + colL;

    const float g1wv = g1w[co], g1bv = g1b[co];
    const float g2wv = g2w[co], g2bv = g2b[co];

    const int h0 = PSLOT(colL);
    const int h1 = PSLOT(16 + colL);
    const int h2 = PSLOT(32 + colL);
    const int h3 = PSLOT(48 + colL);
    const int kq0 = q * 8;

    short8 w1r[18], w2r[18];
#pragma unroll
    for (int i = 0; i < 18; i++) {
        int fidx = (i * 4 + nt) * 64 + lane;
        w1r[i] = ((const short8*)wb1h)[fidx];
        w2r[i] = ((const short8*)wb2h)[fidx];
    }

    for (int i = t; i < HP_PLANE; i += 256) { hp1[i] = 0; hp2[i] = 0; }

    // ---- self-compute r2_g2 stats of raw U7 ----
    const float* up = u7raw + (size_t)n * 3136;
    IN_STATS(up, 49)

    // ---- stage raw U7 with fused r2_g2 GN + ReLU -> hp1 bf16 ----
    for (int i = t; i < 3136; i += 256) {
        int ch = i / 49, r = i - ch * 49;
        int y = r / 7, x = r - y * 7;
        float m = sM[ch >> 1], rs = sR[ch >> 1];
        float v = fmaxf((up[i] - m) * rs * pgw[ch] + pgb[ch], 0.f);
        hp1[((y + 1) * 10 + (x + 1)) * HP_PITCH + ch] = f2bf(v);
    }
    __syncthreads();

    // ---- folded r2_c2 conv + Z7 skip -> register state ----
    f32x4 zr0, zr1, zr2, zr3;
    f32x4 za0, za1, za2, za3;
    f32x4 ur0, ur1, ur2, ur3;
    {
        f32x4 a0, a1, a2, a3;
        CONV_MFMA_G(hp1, wr2h)
        const float* zb = z7 + (size_t)n * 3136 + (size_t)co * 49;
#define INITZ(zm, areg, mm)                                                     \
        _Pragma("unroll")                                                       \
        for (int j = 0; j < 4; j++) {                                           \
            int p_ = (mm) * 16 + q * 4 + j;                                     \
            zm[j] = PVALID(p_) ? (areg[j] + zb[(p_ >> 3) * 7 + (p_ & 7)]) : 0.f;\
        }
        INITZ(zr0, a0, 0) INITZ(zr1, a1, 1) INITZ(zr2, a2, 2) INITZ(zr3, a3, 3)
#undef INITZ
    }
    ur0 = zr0; ur1 = zr1; ur2 = zr2; ur3 = zr3;
    __syncthreads();

    const float dt = 0.5f;

#pragma unroll 1
    for (int step = 0; step < 12; step++) {
#pragma unroll 1
        for (int e = 0; e < 4; e++) {
            const float ck = (e == 0 || e == 3) ? dt / 6.f : dt / 3.f;
            const float cu = (e == 2) ? dt : 0.5f * dt;

            {
                float s = 0.f, s2 = 0.f;
                GN_ACCUM(ur0, 0) GN_ACCUM(ur1, 1) GN_ACCUM(ur2, 2) GN_ACCUM(ur3, 3)
                s += __shfl_xor(s, 16); s2 += __shfl_xor(s2, 16);
                s += __shfl_xor(s, 32); s2 += __shfl_xor(s2, 32);
                float mu = s * (1.f / 49.f);
                float r = rsqrtf(s2 * (1.f / 49.f) - mu * mu + 1e-5f);
                float sc = r * g1wv, sh = g1bv - mu * sc;
                GN_STORE(hp1, ur0, 0) GN_STORE(hp1, ur1, 1)
                GN_STORE(hp1, ur2, 2) GN_STORE(hp1, ur3, 3)
            }
            __syncthreads();   // B1

            {
                f32x4 a0, a1, a2, a3;
                CONV_MFMA(hp1, w1r)

                float s = 0.f, s2 = 0.f;
                GN_ACCUM(a0, 0) GN_ACCUM(a1, 1) GN_ACCUM(a2, 2) GN_ACCUM(a3, 3)
                s += __shfl_xor(s, 16); s2 += __shfl_xor(s2, 16);
                s += __shfl_xor(s, 32); s2 += __shfl_xor(s2, 32);
                float mu = s * (1.f / 49.f);
                float r = rsqrtf(s2 * (1.f / 49.f) - mu * mu + 1e-5f);
                float sc = r * g2wv, sh = g2bv - mu * sc;
                GN_STORE(hp2, a0, 0) GN_STORE(hp2, a1, 1)
                GN_STORE(hp2, a2, 2) GN_STORE(hp2, a3, 3)
            }
            __syncthreads();   // B2

            {
                f32x4 a0, a1, a2, a3;
                CONV_MFMA(hp2, w2r)

                RK4_REG(a0, zr0, za0, ur0) RK4_REG(a1, zr1, za1, ur1)
                RK4_REG(a2, zr2, za2, ur2) RK4_REG(a3, zr3, za3, ur3)
                if (e == 3) {
                    zr0 = za0; zr1 = za1; zr2 = za2; zr3 = za3;
                    ur0 = zr0; ur1 = zr1; ur2 = zr2; ur3 = zr3;
                }
            }
        }
    }

    // ---- final GN(groups=32)+ReLU + mean-pool ----
    {
        float s = 0.f, s2 = 0.f;
        GN_ACCUM(zr0, 0) GN_ACCUM(zr1, 1) GN_ACCUM(zr2, 2) GN_ACCUM(zr3, 3)
        s += __shfl_xor(s, 16); s2 += __shfl_xor(s2, 16);
        s += __shfl_xor(s, 32); s2 += __shfl_xor(s2, 32);
        s += __shfl_xor(s, 1);  s2 += __shfl_xor(s2, 1);
        float mu = s * (1.f / 98.f);
        float r = rsqrtf(s2 * (1.f / 98.f) - mu * mu + 1e-5f);
        float sc = r * fgw[co], sh = fgb[co] - mu * sc;
        float ps = 0.f;
#pragma unroll
        for (int mm = 0; mm < 4; mm++) {
            f32x4 zz = (mm == 0) ? zr0 : (mm == 1) ? zr1 : (mm == 2) ? zr2 : zr3;
#pragma unroll
            for (int j = 0; j < 4; j++) {
                int p_ = mm * 16 + q * 4 + j;
                if (PVALID(p_)) ps += fmaxf(zz[j] * sc + sh, 0.f);
            }
        }
        ps += __shfl_xor(ps, 16);
        ps += __shfl_xor(ps, 32);
        if (q == 0) pooled[co] = ps * (1.f / 49.f);
    }
    __syncthreads();
    if (t < 10) {
        float a = fcb[t];
#pragma unroll
        for (int k = 0; k < 64; k++) a += pooled[k] * fcw[t * 64 + k];
        out[(size_t)n * 10 + t] = a;
    }
}

static inline int nblk(long long total) { return (int)((total + TPB - 1) / TPB); }

extern "C" void kernel_launch(void* const* d_in, const int* in_sizes, int n_in,
                              void* d_out, int out_size, void* d_ws, size_t ws_size,
                              hipStream_t stream) {
    const float* x       = (const float*)d_in[0];
    const float* conv1_w = (const float*)d_in[1];
    const float* conv1_b = (const float*)d_in[2];
    const float* r1_g1w  = (const float*)d_in[3];
    const float* r1_g1b  = (const float*)d_in[4];
    const float* r1_c1w  = (const float*)d_in[5];
    const float* r1_g2w  = (const float*)d_in[6];
    const float* r1_g2b  = (const float*)d_in[7];
    const float* r1_c2w  = (const float*)d_in[8];
    const float* r1_dw   = (const float*)d_in[9];
    const float* r2_g1w  = (const float*)d_in[10];
    const float* r2_g1b  = (const float*)d_in[11];
    const float* r2_c1w  = (const float*)d_in[12];
    const float* r2_g2w  = (const float*)d_in[13];
    const float* r2_g2b  = (const float*)d_in[14];
    const float* r2_c2w  = (const float*)d_in[15];
    const float* r2_dw   = (const float*)d_in[16];
    const float* o_g1w   = (const float*)d_in[17];
    const float* o_g1b   = (const float*)d_in[18];
    const float* o_c1w   = (const float*)d_in[19];
    const float* o_g2w   = (const float*)d_in[20];
    const float* o_g2b   = (const float*)d_in[21];
    const float* o_c2w   = (const float*)d_in[22];
    const float* fin_gw  = (const float*)d_in[23];
    const float* fin_gb  = (const float*)d_in[24];
    const float* fc_w    = (const float*)d_in[25];
    const float* fc_b    = (const float*)d_in[26];
    float* out = (float*)d_out;

    const long long SZ26 = 512LL * 64 * 26 * 26;
    const long long SZ13 = 512LL * 64 * 13 * 13;
    const long long SZ7  = 512LL * 64 * 7 * 7;
    const long long WBS  = 9 * 2 * 4 * 64 * 8;
    const long long WBS1 = 2 * 4 * 64 * 8;

    float* B26   = (float*)d_ws;
    float* A13   = B26 + SZ26;
    float* B13   = A13 + SZ13;
    float* Z7    = B13 + SZ13;
    float* U7    = Z7 + SZ7;
    unsigned short* WTAB  = (unsigned short*)(U7 + SZ7);
    unsigned short* WB1h  = WTAB;               // o_c1w
    unsigned short* WB2h  = WTAB + WBS;         // o_c2w
    unsigned short* WB13h = WTAB + 2 * WBS;     // r1_c2w
    unsigned short* WR2h  = WTAB + 3 * WBS;     // r2_c2w
    unsigned short* WR11h = WTAB + 4 * WBS;     // r1_c1w
    unsigned short* WR21h = WTAB + 5 * WBS;     // r2_c1w
    unsigned short* WD1h  = WTAB + 6 * WBS;     // r1_dw
    unsigned short* WD2h  = WTAB + 6 * WBS + WBS1; // r2_dw

    // ---- all weight prep in one launch ----
    wsplit_all_k<<<nblk(6 * WBS + 2 * WBS1), TPB, 0, stream>>>(
        o_c1w, o_c2w, r1_c2w, r2_c2w, r1_c1w, r2_c1w, r1_dw, r2_dw, WTAB);

    // ---- stage 0: conv1 ----
    conv1_k<<<nblk(SZ26), TPB, 0, stream>>>(x, conv1_w, conv1_b, B26);

    // ---- residual block 1: 26x26 -> 13x13 ----
    conv_s2_mfma_k<<<512 * 4, 256, 0, stream>>>(B26, WR11h, WD1h, A13, B13,
                                                r1_g1w, r1_g1b, 26, 26, 13, 13, 2, 2);
    conv13_mfma_k<<<512, 256, 0, stream>>>(A13, WB13h, B13, r1_g2w, r1_g2b);

    // ---- residual block 2: 13x13 -> 7x7 ----
    conv_s2_mfma_k<<<512, 256, 0, stream>>>(B13, WR21h, WD2h, U7, Z7,
                                            r2_g1w, r2_g1b, 13, 13, 7, 7, 1, 1);

    // ---- fused: GN + r2_c2 conv + skip + ODE RK4 + final GN + pool + FC ----
    ode_mfma_k<<<512, 256, 0, stream>>>(U7, Z7, r2_g2w, r2_g2b,
                                        WR2h, WB1h, WB2h,
                                        o_g1w, o_g1b, o_g2w, o_g2b,
                                        fin_gw, fin_gb, fc_w, fc_b, out);
}

// Round 16
// 607.537 us; speedup vs baseline: 1.1105x; 1.1105x over previous
//
#include <hip/hip_runtime.h>
#include <hip/hip_bf16.h>

#define TPB 256

typedef __attribute__((ext_vector_type(8))) short short8;
typedef __attribute__((ext_vector_type(4))) float f32x4;

__device__ __forceinline__ unsigned short f2bf(float x) {
    union { float f; unsigned int u; } c; c.f = x;
    unsigned int u = c.u;
    unsigned int r = (u + 0x7fffu + ((u >> 16) & 1u)) >> 16;
    return (unsigned short)r;
}

// ---- in-block GN stats (C=64, G=32): X image base -> sM[32], sR[32] ----
#define IN_STATS(Xp, HW)                                                        \
    {                                                                           \
        int ch_ = t >> 2, sg_ = t & 3;                                          \
        float s_ = 0.f, s2_ = 0.f;                                              \
        for (int i_ = sg_; i_ < (HW); i_ += 4) {                                \
            float v_ = (Xp)[(size_t)ch_ * (HW) + i_];                           \
            s_ += v_; s2_ += v_ * v_;                                           \
        }                                                                       \
        rsum[t] = s_; rssq[t] = s2_;                                            \
        __syncthreads();                                                        \
        if (t < 32) {                                                           \
            float S = 0.f, S2 = 0.f;                                            \
            _Pragma("unroll")                                                   \
            for (int k_ = 0; k_ < 8; k_++) {                                    \
                int tt_ = (2 * t + (k_ & 1)) * 4 + (k_ >> 1);                   \
                S += rsum[tt_]; S2 += rssq[tt_];                                \
            }                                                                   \
            float mu_ = S / (2.f * (HW));                                       \
            sM[t] = mu_;                                                        \
            sR[t] = rsqrtf(S2 / (2.f * (HW)) - mu_ * mu_ + 1e-5f);              \
        }                                                                       \
        __syncthreads();                                                        \
    }

// ======================= conv1 ===============================================

__global__ void conv1_k(const float* __restrict__ x, const float* __restrict__ w,
                        const float* __restrict__ b, float* __restrict__ out) {
    int idx = blockIdx.x * TPB + threadIdx.x;
    const int total = 512 * 64 * 26 * 26;
    if (idx >= total) return;
    int ox = idx % 26; int t = idx / 26;
    int oy = t % 26;   t /= 26;
    int co = t % 64;   int n = t / 64;
    const float* xp = x + (size_t)n * 784 + oy * 28 + ox;
    const float* wp = w + co * 9;
    float s = b[co];
#pragma unroll
    for (int ky = 0; ky < 3; ky++)
#pragma unroll
        for (int kx = 0; kx < 3; kx++)
            s += xp[ky * 28 + kx] * wp[ky * 3 + kx];
    out[idx] = s;
}

// ======================= separate GN stats (for multi-block consumers) =======

__global__ void gn_stats_k(const float* __restrict__ x, float* __restrict__ mean,
                           float* __restrict__ rstd, int N, int C, int HW, int G) {
    int gid  = (blockIdx.x * blockDim.x + threadIdx.x) >> 6;
    int lane = threadIdx.x & 63;
    int total = N * G;
    if (gid >= total) return;
    int n = gid / G, g = gid % G;
    int cpg = C / G;
    int gsize = cpg * HW;
    const float* p = x + ((size_t)n * C + (size_t)g * cpg) * HW;
    float s = 0.f, s2 = 0.f;
    for (int i = lane; i < gsize; i += 64) { float v = p[i]; s += v; s2 += v * v; }
#pragma unroll
    for (int off = 32; off; off >>= 1) {
        s  += __shfl_down(s,  off);
        s2 += __shfl_down(s2, off);
    }
    if (lane == 0) {
        float m = s / gsize;
        float var = s2 / gsize - m * m;
        mean[gid] = m;
        rstd[gid] = rsqrtf(var + 1e-5f);
    }
}

// ======================= combined weight prep ================================

__global__ void wsplit_all_k(const float* __restrict__ w0, const float* __restrict__ w1,
                             const float* __restrict__ w2, const float* __restrict__ w3,
                             const float* __restrict__ w4, const float* __restrict__ w5,
                             const float* __restrict__ d0, const float* __restrict__ d1,
                             unsigned short* __restrict__ dst) {
    const int WBS = 9 * 2 * 4 * 64 * 8, WBS1 = 2 * 4 * 64 * 8;
    int i = blockIdx.x * TPB + threadIdx.x;
    if (i < 6 * WBS) {
        int tbl = i / WBS; int r = i - tbl * WBS;
        const float* w = (tbl == 0) ? w0 : (tbl == 1) ? w1 : (tbl == 2) ? w2
                       : (tbl == 3) ? w3 : (tbl == 4) ? w4 : w5;
        int j = r & 7, l = (r >> 3) & 63, nt = (r >> 9) & 3, ks = (r >> 11) & 1, tt = r >> 12;
        int co = nt * 16 + (l & 15);
        int ci = ks * 32 + (l >> 4) * 8 + j;
        dst[i] = f2bf(w[(co * 64 + ci) * 9 + tt]);
    } else {
        int r = i - 6 * WBS;
        if (r >= 2 * WBS1) return;
        int tbl = r / WBS1; r -= tbl * WBS1;
        const float* w = tbl ? d1 : d0;
        int j = r & 7, l = (r >> 3) & 63, nt = (r >> 9) & 3, ks = (r >> 11) & 1;
        int co = nt * 16 + (l & 15);
        int ci = ks * 32 + (l >> 4) * 8 + j;
        dst[6 * WBS + tbl * WBS1 + r] = f2bf(w[co * 64 + ci]);
    }
}

// ======================= stride-2 MFMA conv (+GN, +1x1 skip) =================
// SELF=true: compute GN stats in-block (valid only when 1 block per image).
// SELF=false: read precomputed mean/rstd (multi-block-per-image case).

template<bool SELF>
__global__ __launch_bounds__(256, 2)
void conv_s2_mfma_k(const float* __restrict__ in,
                    const unsigned short* __restrict__ bhT,
                    const unsigned short* __restrict__ dwT,
                    float* __restrict__ out, float* __restrict__ skipout,
                    const float* __restrict__ mean, const float* __restrict__ rstd,
                    const float* __restrict__ gnw, const float* __restrict__ gnb,
                    int H, int W, int OH, int OW, int TX, int TY) {
    __shared__ unsigned short hp[256 * 72];
    __shared__ float rsum[256], rssq[256], sM[32], sR[32];

    int b = blockIdx.x;
    int tx = b % TX; b /= TX;
    int ty = b % TY; int n = b / TY;
    int oy0 = ty * 7, ox0 = tx * 7;

    const int t = threadIdx.x;
    const int lane = t & 63, nt = t >> 6;
    const int colL = lane & 15, q = lane >> 4;
    const int co = nt * 16 + colL;
    const int kq0 = q * 8;

    short8 wr[18], dr[2];
#pragma unroll
    for (int i = 0; i < 18; i++) wr[i] = ((const short8*)bhT)[(i * 4 + nt) * 64 + lane];
    dr[0] = ((const short8*)dwT)[(0 * 4 + nt) * 64 + lane];
    dr[1] = ((const short8*)dwT)[(1 * 4 + nt) * 64 + lane];

    for (int i = t; i < 256 * 72 / 2; i += 256) ((unsigned int*)hp)[i] = 0u;

    const float* ip = in + (size_t)n * 64 * H * W;
    if constexpr (SELF) {
        IN_STATS(ip, H * W)
    } else {
        if (t < 32) { sM[t] = mean[n * 32 + t]; sR[t] = rstd[n * 32 + t]; }
        __syncthreads();
    }

    // ---- stage 15x16 phase-split tile with fused GN+ReLU ----
    for (int i = t; i < 64 * 240; i += 256) {
        int ch = i / 240; int rc = i - ch * 240;
        int r = rc >> 4, c = rc & 15;
        int iy = 2 * oy0 - 1 + r;
        int ix = (c < 8) ? (2 * ox0 + 2 * c) : (2 * ox0 - 1 + 2 * (c - 8));
        if ((unsigned)iy < (unsigned)H && (unsigned)ix < (unsigned)W) {
            float m = sM[ch >> 1], rs = sR[ch >> 1];
            float raw = ip[(size_t)ch * H * W + iy * W + ix];
            float v = fmaxf((raw - m) * rs * gnw[ch] + gnb[ch], 0.f);
            hp[(r * 16 + c) * 72 + ch] = f2bf(v);
        }
    }
    __syncthreads();

    int bs0, bs1, bs2, bs3;
    {
#define BSLOT(dst, mm)                                                          \
        {                                                                       \
            int p_ = (mm) * 16 + colL;                                          \
            int oy_ = p_ >> 3, ox_ = p_ & 7;                                    \
            dst = (ox_ < 7 && oy_ < 7) ? ((2 * oy_) * 16 + ox_) : 0;            \
        }
        BSLOT(bs0, 0) BSLOT(bs1, 1) BSLOT(bs2, 2) BSLOT(bs3, 3)
#undef BSLOT
    }

    f32x4 a0, a1, a2, a3, k0, k1, k2, k3;
    a0 = (f32x4){0.f, 0.f, 0.f, 0.f}; a1 = a0; a2 = a0; a3 = a0;
    k0 = a0; k1 = a0; k2 = a0; k3 = a0;

#pragma unroll
    for (int t9 = 0; t9 < 9; t9++) {
        const int kx = t9 % 3;
        const int toff = (t9 / 3) * 16 + (kx == 0 ? 8 : (kx == 1 ? 0 : 9));
#pragma unroll
        for (int ks = 0; ks < 2; ks++) {
            short8 vb = wr[t9 * 2 + ks];
            int kq = ks * 32 + kq0;
#define TAP(areg, bs)                                                           \
            {                                                                   \
                short8 av = *(const short8*)(hp + ((bs) + toff) * 72 + kq);     \
                areg = __builtin_amdgcn_mfma_f32_16x16x32_bf16(av, vb, areg, 0, 0, 0); \
            }
            TAP(a0, bs0) TAP(a1, bs1) TAP(a2, bs2) TAP(a3, bs3)
#undef TAP
        }
    }
#pragma unroll
    for (int ks = 0; ks < 2; ks++) {
        short8 vb = dr[ks];
        int kq = ks * 32 + kq0;
#define TAP(areg, bs)                                                           \
        {                                                                       \
            short8 av = *(const short8*)(hp + ((bs) + 16) * 72 + kq);           \
            areg = __builtin_amdgcn_mfma_f32_16x16x32_bf16(av, vb, areg, 0, 0, 0); \
        }
        TAP(k0, bs0) TAP(k1, bs1) TAP(k2, bs2) TAP(k3, bs3)
#undef TAP
    }

#define WB(areg, kreg, mm)                                                      \
    _Pragma("unroll")                                                           \
    for (int j = 0; j < 4; j++) {                                               \
        int p_ = (mm) * 16 + q * 4 + j;                                         \
        int oy_ = p_ >> 3, ox_ = p_ & 7;                                        \
        if (ox_ < 7 && oy_ < 7 && oy0 + oy_ < OH && ox0 + ox_ < OW) {           \
            size_t idx = (((size_t)n * 64 + co) * OH + oy0 + oy_) * OW + ox0 + ox_; \
            out[idx] = areg[j];                                                 \
            skipout[idx] = kreg[j];                                             \
        }                                                                       \
    }
    WB(a0, k0, 0) WB(a1, k1, 1) WB(a2, k2, 2) WB(a3, k3, 3)
#undef WB
}

// ======================= 13x13 MFMA conv (r1_c2, self GN) ====================

__global__ __launch_bounds__(256, 2)
void conv13_mfma_k(const float* __restrict__ in, const unsigned short* __restrict__ bhT,
                   float* __restrict__ io,
                   const float* __restrict__ gnw, const float* __restrict__ gnb) {
    __shared__ unsigned short hp[256 * 72];
    __shared__ float rsum[256], rssq[256], sM[32], sR[32];
    const int t = threadIdx.x;
    const int n = blockIdx.x;
    const int lane = t & 63;
    const int nt = t >> 6;
    const int colL = lane & 15, q = lane >> 4;
    const int co = nt * 16 + colL;
    const int kq0 = q * 8;

    short8 wr[18];
#pragma unroll
    for (int i = 0; i < 18; i++) wr[i] = ((const short8*)bhT)[(i * 4 + nt) * 64 + lane];

    for (int i = t; i < 256 * 72 / 2; i += 256) ((unsigned int*)hp)[i] = 0u;

    const float* ip = in + (size_t)n * 64 * 169;
    IN_STATS(ip, 169)

    for (int i = t; i < 64 * 169; i += 256) {
        int ch = i / 169, p = i - ch * 169;
        int y = p / 13, x = p - y * 13;
        float m = sM[ch >> 1], rs = sR[ch >> 1];
        float v = fmaxf((ip[i] - m) * rs * gnw[ch] + gnb[ch], 0.f);
        hp[((y + 1) * 16 + (x + 1)) * 72 + ch] = f2bf(v);
    }
    __syncthreads();

    int hb[11];
#pragma unroll
    for (int m = 0; m < 11; m++) {
        int p = m * 16 + colL;
        int y = p / 13, x = p - y * 13;
        hb[m] = (y + 1) * 16 + (x + 1);
    }
    f32x4 acc[11];
#pragma unroll
    for (int m = 0; m < 11; m++) acc[m] = (f32x4){0.f, 0.f, 0.f, 0.f};

#pragma unroll
    for (int t9 = 0; t9 < 9; t9++) {
        const int toff = (t9 / 3) * 16 + (t9 % 3) - 17;
#pragma unroll
        for (int ks = 0; ks < 2; ks++) {
            short8 vb = wr[t9 * 2 + ks];
            int kq = ks * 32 + kq0;
#pragma unroll
            for (int m = 0; m < 11; m++) {
                short8 a_ = *(const short8*)(hp + (hb[m] + toff) * 72 + kq);
                acc[m] = __builtin_amdgcn_mfma_f32_16x16x32_bf16(a_, vb, acc[m], 0, 0, 0);
            }
        }
    }

    float* op = io + (size_t)n * 64 * 169 + (size_t)co * 169;
#pragma unroll
    for (int m = 0; m < 11; m++) {
        int p0 = m * 16 + q * 4;
#pragma unroll
        for (int j = 0; j < 4; j++) {
            int p = p0 + j;
            if (p < 169) op[p] += acc[m][j];
        }
    }
}

// ======================= ODE MFMA mega-kernel ================================

#define HP_PITCH 72
#define HP_PLANE (100 * HP_PITCH)

#define PVALID(p) ((((p) & 7) < 7) && (((p) >> 3) < 7))
#define PSLOT(p)  (((((p) >> 3) + 1) * 10) + (((p) & 7) + 1))

#define CONV_TAP(areg, hbase)                                                   \
    {                                                                           \
        short8 a_ = *(const short8*)(hp + ((hbase) + toff) * HP_PITCH + kq);    \
        areg = __builtin_amdgcn_mfma_f32_16x16x32_bf16(a_, vb, areg, 0, 0, 0);  \
    }

#define CONV_MFMA(hpsrc, wreg)                                                  \
    a0 = (f32x4){0.f, 0.f, 0.f, 0.f}; a1 = a0; a2 = a0; a3 = a0;                \
    {                                                                           \
        const unsigned short* hp = (hpsrc);                                     \
        _Pragma("unroll")                                                       \
        for (int t9 = 0; t9 < 9; t9++) {                                        \
            const int toff = (t9 / 3) * 10 + (t9 % 3) - 11;                     \
            _Pragma("unroll")                                                   \
            for (int ks = 0; ks < 2; ks++) {                                    \
                short8 vb = wreg[t9 * 2 + ks];                                  \
                int kq = ks * 32 + kq0;                                         \
                CONV_TAP(a0, h0)                                                \
                CONV_TAP(a1, h1)                                                \
                CONV_TAP(a2, h2)                                                \
                CONV_TAP(a3, h3)                                                \
            }                                                                   \
        }                                                                       \
    }

#define CONV_MFMA_G(hpsrc, bhT)                                                 \
    a0 = (f32x4){0.f, 0.f, 0.f, 0.f}; a1 = a0; a2 = a0; a3 = a0;                \
    {                                                                           \
        const unsigned short* hp = (hpsrc);                                     \
        const short8* bh_ = (const short8*)(bhT);                               \
        _Pragma("unroll")                                                       \
        for (int t9 = 0; t9 < 9; t9++) {                                        \
            const int toff = (t9 / 3) * 10 + (t9 % 3) - 11;                     \
            _Pragma("unroll")                                                   \
            for (int ks = 0; ks < 2; ks++) {                                    \
                short8 vb = bh_[((t9 * 2 + ks) * 4 + nt) * 64 + lane];          \
                int kq = ks * 32 + kq0;                                         \
                CONV_TAP(a0, h0)                                                \
                CONV_TAP(a1, h1)                                                \
                CONV_TAP(a2, h2)                                                \
                CONV_TAP(a3, h3)                                                \
            }                                                                   \
        }                                                                       \
    }

#define GN_ACCUM(areg, mm)                                                      \
    _Pragma("unroll")                                                           \
    for (int j = 0; j < 4; j++) {                                               \
        int p_ = (mm) * 16 + q * 4 + j;                                         \
        if (PVALID(p_)) { float x_ = areg[j]; s += x_; s2 += x_ * x_; }         \
    }

#define GN_STORE(dst, areg, mm)                                                 \
    _Pragma("unroll")                                                           \
    for (int j = 0; j < 4; j++) {                                               \
        int p_ = (mm) * 16 + q * 4 + j;                                         \
        if (PVALID(p_)) {                                                       \
            float y_ = fmaxf(areg[j] * sc + sh, 0.f);                           \
            (dst)[PSLOT(p_) * HP_PITCH + co] = f2bf(y_);                        \
        }                                                                       \
    }

#define RK4_REG(areg, zm, zam, um)                                              \
    {                                                                           \
        f32x4 kv = areg + um;                                                   \
        zam = (e == 0) ? (zm + ck * kv) : (zam + ck * kv);                      \
        if (e < 3) um = zm + cu * kv;                                           \
    }

__global__ __launch_bounds__(256, 2)
void ode_mfma_k(const float* __restrict__ u7raw, const float* __restrict__ z7,
                const float* __restrict__ pgw, const float* __restrict__ pgb,
                const unsigned short* __restrict__ wr2h,
                const unsigned short* __restrict__ wb1h,
                const unsigned short* __restrict__ wb2h,
                const float* __restrict__ g1w, const float* __restrict__ g1b,
                const float* __restrict__ g2w, const float* __restrict__ g2b,
                const float* __restrict__ fgw, const float* __restrict__ fgb,
                const float* __restrict__ fcw, const float* __restrict__ fcb,
                float* __restrict__ out) {
    __shared__ unsigned short hp1[HP_PLANE], hp2[HP_PLANE];
    __shared__ float rsum[256], rssq[256], sM[32], sR[32];
    __shared__ float pooled[64];

    const int t = threadIdx.x;
    const int n = blockIdx.x;
    const int lane = t & 63;
    const int nt = t >> 6;
    const int colL = lane & 15, q = lane >> 4;
    const int co = nt * 16 + colL;

    const float g1wv = g1w[co], g1bv = g1b[co];
    const float g2wv = g2w[co], g2bv = g2b[co];

    const int h0 = PSLOT(colL);
    const int h1 = PSLOT(16 + colL);
    const int h2 = PSLOT(32 + colL);
    const int h3 = PSLOT(48 + colL);
    const int kq0 = q * 8;

    short8 w1r[18], w2r[18];
#pragma unroll
    for (int i = 0; i < 18; i++) {
        int fidx = (i * 4 + nt) * 64 + lane;
        w1r[i] = ((const short8*)wb1h)[fidx];
        w2r[i] = ((const short8*)wb2h)[fidx];
    }

    for (int i = t; i < HP_PLANE; i += 256) { hp1[i] = 0; hp2[i] = 0; }

    const float* up = u7raw + (size_t)n * 3136;
    IN_STATS(up, 49)

    for (int i = t; i < 3136; i += 256) {
        int ch = i / 49, r = i - ch * 49;
        int y = r / 7, x = r - y * 7;
        float m = sM[ch >> 1], rs = sR[ch >> 1];
        float v = fmaxf((up[i] - m) * rs * pgw[ch] + pgb[ch], 0.f);
        hp1[((y + 1) * 10 + (x + 1)) * HP_PITCH + ch] = f2bf(v);
    }
    __syncthreads();

    f32x4 zr0, zr1, zr2, zr3;
    f32x4 za0, za1, za2, za3;
    f32x4 ur0, ur1, ur2, ur3;
    {
        f32x4 a0, a1, a2, a3;
        CONV_MFMA_G(hp1, wr2h)
        const float* zb = z7 + (size_t)n * 3136 + (size_t)co * 49;
#define INITZ(zm, areg, mm)                                                     \
        _Pragma("unroll")                                                       \
        for (int j = 0; j < 4; j++) {                                           \
            int p_ = (mm) * 16 + q * 4 + j;                                     \
            zm[j] = PVALID(p_) ? (areg[j] + zb[(p_ >> 3) * 7 + (p_ & 7)]) : 0.f;\
        }
        INITZ(zr0, a0, 0) INITZ(zr1, a1, 1) INITZ(zr2, a2, 2) INITZ(zr3, a3, 3)
#undef INITZ
    }
    ur0 = zr0; ur1 = zr1; ur2 = zr2; ur3 = zr3;
    __syncthreads();

    const float dt = 0.5f;

#pragma unroll 1
    for (int step = 0; step < 12; step++) {
#pragma unroll 1
        for (int e = 0; e < 4; e++) {
            const float ck = (e == 0 || e == 3) ? dt / 6.f : dt / 3.f;
            const float cu = (e == 2) ? dt : 0.5f * dt;

            {
                float s = 0.f, s2 = 0.f;
                GN_ACCUM(ur0, 0) GN_ACCUM(ur1, 1) GN_ACCUM(ur2, 2) GN_ACCUM(ur3, 3)
                s += __shfl_xor(s, 16); s2 += __shfl_xor(s2, 16);
                s += __shfl_xor(s, 32); s2 += __shfl_xor(s2, 32);
                float mu = s * (1.f / 49.f);
                float r = rsqrtf(s2 * (1.f / 49.f) - mu * mu + 1e-5f);
                float sc = r * g1wv, sh = g1bv - mu * sc;
                GN_STORE(hp1, ur0, 0) GN_STORE(hp1, ur1, 1)
                GN_STORE(hp1, ur2, 2) GN_STORE(hp1, ur3, 3)
            }
            __syncthreads();   // B1

            {
                f32x4 a0, a1, a2, a3;
                CONV_MFMA(hp1, w1r)

                float s = 0.f, s2 = 0.f;
                GN_ACCUM(a0, 0) GN_ACCUM(a1, 1) GN_ACCUM(a2, 2) GN_ACCUM(a3, 3)
                s += __shfl_xor(s, 16); s2 += __shfl_xor(s2, 16);
                s += __shfl_xor(s, 32); s2 += __shfl_xor(s2, 32);
                float mu = s * (1.f / 49.f);
                float r = rsqrtf(s2 * (1.f / 49.f) - mu * mu + 1e-5f);
                float sc = r * g2wv, sh = g2bv - mu * sc;
                GN_STORE(hp2, a0, 0) GN_STORE(hp2, a1, 1)
                GN_STORE(hp2, a2, 2) GN_STORE(hp2, a3, 3)
            }
            __syncthreads();   // B2

            {
                f32x4 a0, a1, a2, a3;
                CONV_MFMA(hp2, w2r)

                RK4_REG(a0, zr0, za0, ur0) RK4_REG(a1, zr1, za1, ur1)
                RK4_REG(a2, zr2, za2, ur2) RK4_REG(a3, zr3, za3, ur3)
                if (e == 3) {
                    zr0 = za0; zr1 = za1; zr2 = za2; zr3 = za3;
                    ur0 = zr0; ur1 = zr1; ur2 = zr2; ur3 = zr3;
                }
            }
        }
    }

    {
        float s = 0.f, s2 = 0.f;
        GN_ACCUM(zr0, 0) GN_ACCUM(zr1, 1) GN_ACCUM(zr2, 2) GN_ACCUM(zr3, 3)
        s += __shfl_xor(s, 16); s2 += __shfl_xor(s2, 16);
        s += __shfl_xor(s, 32); s2 += __shfl_xor(s2, 32);
        s += __shfl_xor(s, 1);  s2 += __shfl_xor(s2, 1);
        float mu = s * (1.f / 98.f);
        float r = rsqrtf(s2 * (1.f / 98.f) - mu * mu + 1e-5f);
        float sc = r * fgw[co], sh = fgb[co] - mu * sc;
        float ps = 0.f;
#pragma unroll
        for (int mm = 0; mm < 4; mm++) {
            f32x4 zz = (mm == 0) ? zr0 : (mm == 1) ? zr1 : (mm == 2) ? zr2 : zr3;
#pragma unroll
            for (int j = 0; j < 4; j++) {
                int p_ = mm * 16 + q * 4 + j;
                if (PVALID(p_)) ps += fmaxf(zz[j] * sc + sh, 0.f);
            }
        }
        ps += __shfl_xor(ps, 16);
        ps += __shfl_xor(ps, 32);
        if (q == 0) pooled[co] = ps * (1.f / 49.f);
    }
    __syncthreads();
    if (t < 10) {
        float a = fcb[t];
#pragma unroll
        for (int k = 0; k < 64; k++) a += pooled[k] * fcw[t * 64 + k];
        out[(size_t)n * 10 + t] = a;
    }
}

static inline int nblk(long long total) { return (int)((total + TPB - 1) / TPB); }

extern "C" void kernel_launch(void* const* d_in, const int* in_sizes, int n_in,
                              void* d_out, int out_size, void* d_ws, size_t ws_size,
                              hipStream_t stream) {
    const float* x       = (const float*)d_in[0];
    const float* conv1_w = (const float*)d_in[1];
    const float* conv1_b = (const float*)d_in[2];
    const float* r1_g1w  = (const float*)d_in[3];
    const float* r1_g1b  = (const float*)d_in[4];
    const float* r1_c1w  = (const float*)d_in[5];
    const float* r1_g2w  = (const float*)d_in[6];
    const float* r1_g2b  = (const float*)d_in[7];
    const float* r1_c2w  = (const float*)d_in[8];
    const float* r1_dw   = (const float*)d_in[9];
    const float* r2_g1w  = (const float*)d_in[10];
    const float* r2_g1b  = (const float*)d_in[11];
    const float* r2_c1w  = (const float*)d_in[12];
    const float* r2_g2w  = (const float*)d_in[13];
    const float* r2_g2b  = (const float*)d_in[14];
    const float* r2_c2w  = (const float*)d_in[15];
    const float* r2_dw   = (const float*)d_in[16];
    const float* o_g1w   = (const float*)d_in[17];
    const float* o_g1b   = (const float*)d_in[18];
    const float* o_c1w   = (const float*)d_in[19];
    const float* o_g2w   = (const float*)d_in[20];
    const float* o_g2b   = (const float*)d_in[21];
    const float* o_c2w   = (const float*)d_in[22];
    const float* fin_gw  = (const float*)d_in[23];
    const float* fin_gb  = (const float*)d_in[24];
    const float* fc_w    = (const float*)d_in[25];
    const float* fc_b    = (const float*)d_in[26];
    float* out = (float*)d_out;

    const long long SZ26 = 512LL * 64 * 26 * 26;
    const long long SZ13 = 512LL * 64 * 13 * 13;
    const long long SZ7  = 512LL * 64 * 7 * 7;
    const long long WBS  = 9 * 2 * 4 * 64 * 8;
    const long long WBS1 = 2 * 4 * 64 * 8;

    float* B26   = (float*)d_ws;
    float* A13   = B26 + SZ26;
    float* B13   = A13 + SZ13;
    float* Z7    = B13 + SZ13;
    float* U7    = Z7 + SZ7;
    float* MEAN  = U7 + SZ7;
    float* RSTD  = MEAN + 512 * 32;
    unsigned short* WTAB  = (unsigned short*)(RSTD + 512 * 32);
    unsigned short* WB1h  = WTAB;               // o_c1w
    unsigned short* WB2h  = WTAB + WBS;         // o_c2w
    unsigned short* WB13h = WTAB + 2 * WBS;     // r1_c2w
    unsigned short* WR2h  = WTAB + 3 * WBS;     // r2_c2w
    unsigned short* WR11h = WTAB + 4 * WBS;     // r1_c1w
    unsigned short* WR21h = WTAB + 5 * WBS;     // r2_c1w
    unsigned short* WD1h  = WTAB + 6 * WBS;     // r1_dw
    unsigned short* WD2h  = WTAB + 6 * WBS + WBS1; // r2_dw

    wsplit_all_k<<<nblk(6 * WBS + 2 * WBS1), TPB, 0, stream>>>(
        o_c1w, o_c2w, r1_c2w, r2_c2w, r1_c1w, r2_c1w, r1_dw, r2_dw, WTAB);

    conv1_k<<<nblk(SZ26), TPB, 0, stream>>>(x, conv1_w, conv1_b, B26);

    // ---- residual block 1: 26x26 -> 13x13 (4 blocks/image -> shared stats) --
    gn_stats_k<<<nblk(512LL * 32 * 64), TPB, 0, stream>>>(B26, MEAN, RSTD, 512, 64, 676, 32);
    conv_s2_mfma_k<false><<<512 * 4, 256, 0, stream>>>(B26, WR11h, WD1h, A13, B13,
                                                       MEAN, RSTD, r1_g1w, r1_g1b,
                                                       26, 26, 13, 13, 2, 2);
    conv13_mfma_k<<<512, 256, 0, stream>>>(A13, WB13h, B13, r1_g2w, r1_g2b);

    // ---- residual block 2: 13x13 -> 7x7 (1 block/image -> self stats) -------
    conv_s2_mfma_k<true><<<512, 256, 0, stream>>>(B13, WR21h, WD2h, U7, Z7,
                                                  nullptr, nullptr, r2_g1w, r2_g1b,
                                                  13, 13, 7, 7, 1, 1);

    // ---- fused: GN + r2_c2 conv + skip + ODE RK4 + final GN + pool + FC ----
    ode_mfma_k<<<512, 256, 0, stream>>>(U7, Z7, r2_g2w, r2_g2b,
                                        WR2h, WB1h, WB2h,
                                        o_g1w, o_g1b, o_g2w, o_g2b,
                                        fin_gw, fin_gb, fc_w, fc_b, out);
}

// Round 17
// 581.582 us; speedup vs baseline: 1.1601x; 1.0446x over previous
//
#include <hip/hip_runtime.h>
#include <hip/hip_bf16.h>

#define TPB 256

typedef __attribute__((ext_vector_type(8))) short short8;
typedef __attribute__((ext_vector_type(4))) float f32x4;

__device__ __forceinline__ unsigned short f2bf(float x) {
    union { float f; unsigned int u; } c; c.f = x;
    unsigned int u = c.u;
    unsigned int r = (u + 0x7fffu + ((u >> 16) & 1u)) >> 16;
    return (unsigned short)r;
}
__device__ __forceinline__ float bf2f(unsigned short h) {
    union { unsigned int u; float f; } c; c.u = ((unsigned int)h) << 16;
    return c.f;
}

// ---- in-block GN stats from a bf16 tensor (C=64, G=32) -> sM[32], sR[32] ----
#define IN_STATS_BF(Xp, HW)                                                     \
    {                                                                           \
        int ch_ = t >> 2, sg_ = t & 3;                                          \
        float s_ = 0.f, s2_ = 0.f;                                              \
        for (int i_ = sg_; i_ < (HW); i_ += 4) {                                \
            float v_ = bf2f((Xp)[(size_t)ch_ * (HW) + i_]);                     \
            s_ += v_; s2_ += v_ * v_;                                           \
        }                                                                       \
        rsum[t] = s_; rssq[t] = s2_;                                            \
        __syncthreads();                                                        \
        if (t < 32) {                                                           \
            float S = 0.f, S2 = 0.f;                                            \
            _Pragma("unroll")                                                   \
            for (int k_ = 0; k_ < 8; k_++) {                                    \
                int tt_ = (2 * t + (k_ & 1)) * 4 + (k_ >> 1);                   \
                S += rsum[tt_]; S2 += rssq[tt_];                                \
            }                                                                   \
            float mu_ = S / (2.f * (HW));                                       \
            sM[t] = mu_;                                                        \
            sR[t] = rsqrtf(S2 / (2.f * (HW)) - mu_ * mu_ + 1e-5f);              \
        }                                                                       \
        __syncthreads();                                                        \
    }

// ======================= conv1 (bf16 output) =================================

__global__ void conv1_k(const float* __restrict__ x, const float* __restrict__ w,
                        const float* __restrict__ b, unsigned short* __restrict__ out) {
    int idx = blockIdx.x * TPB + threadIdx.x;
    const int total = 512 * 64 * 26 * 26;
    if (idx >= total) return;
    int ox = idx % 26; int t = idx / 26;
    int oy = t % 26;   t /= 26;
    int co = t % 64;   int n = t / 64;
    const float* xp = x + (size_t)n * 784 + oy * 28 + ox;
    const float* wp = w + co * 9;
    float s = b[co];
#pragma unroll
    for (int ky = 0; ky < 3; ky++)
#pragma unroll
        for (int kx = 0; kx < 3; kx++)
            s += xp[ky * 28 + kx] * wp[ky * 3 + kx];
    out[idx] = f2bf(s);
}

// ======================= GN stats over bf16 tensor (multi-block consumers) ===

__global__ void gn_stats_bf_k(const unsigned short* __restrict__ x,
                              float* __restrict__ mean, float* __restrict__ rstd,
                              int N, int C, int HW, int G) {
    int gid  = (blockIdx.x * blockDim.x + threadIdx.x) >> 6;
    int lane = threadIdx.x & 63;
    int total = N * G;
    if (gid >= total) return;
    int n = gid / G, g = gid % G;
    int cpg = C / G;
    int gsize = cpg * HW;
    const unsigned short* p = x + ((size_t)n * C + (size_t)g * cpg) * HW;
    float s = 0.f, s2 = 0.f;
    for (int i = lane; i < gsize; i += 64) { float v = bf2f(p[i]); s += v; s2 += v * v; }
#pragma unroll
    for (int off = 32; off; off >>= 1) {
        s  += __shfl_down(s,  off);
        s2 += __shfl_down(s2, off);
    }
    if (lane == 0) {
        float m = s / gsize;
        float var = s2 / gsize - m * m;
        mean[gid] = m;
        rstd[gid] = rsqrtf(var + 1e-5f);
    }
}

// ======================= combined weight prep ================================

__global__ void wsplit_all_k(const float* __restrict__ w0, const float* __restrict__ w1,
                             const float* __restrict__ w2, const float* __restrict__ w3,
                             const float* __restrict__ w4, const float* __restrict__ w5,
                             const float* __restrict__ d0, const float* __restrict__ d1,
                             unsigned short* __restrict__ dst) {
    const int WBS = 9 * 2 * 4 * 64 * 8, WBS1 = 2 * 4 * 64 * 8;
    int i = blockIdx.x * TPB + threadIdx.x;
    if (i < 6 * WBS) {
        int tbl = i / WBS; int r = i - tbl * WBS;
        const float* w = (tbl == 0) ? w0 : (tbl == 1) ? w1 : (tbl == 2) ? w2
                       : (tbl == 3) ? w3 : (tbl == 4) ? w4 : w5;
        int j = r & 7, l = (r >> 3) & 63, nt = (r >> 9) & 3, ks = (r >> 11) & 1, tt = r >> 12;
        int co = nt * 16 + (l & 15);
        int ci = ks * 32 + (l >> 4) * 8 + j;
        dst[i] = f2bf(w[(co * 64 + ci) * 9 + tt]);
    } else {
        int r = i - 6 * WBS;
        if (r >= 2 * WBS1) return;
        int tbl = r / WBS1; r -= tbl * WBS1;
        const float* w = tbl ? d1 : d0;
        int j = r & 7, l = (r >> 3) & 63, nt = (r >> 9) & 3, ks = (r >> 11) & 1;
        int co = nt * 16 + (l & 15);
        int ci = ks * 32 + (l >> 4) * 8 + j;
        dst[6 * WBS + tbl * WBS1 + r] = f2bf(w[co * 64 + ci]);
    }
}

// ======================= stride-2 MFMA conv (+GN, +1x1 skip) =================
// Input/outputs bf16 (except Z7-producing skipout stays fp32 when FP32SKIP).

template<bool SELF, bool FP32SKIP>
__global__ __launch_bounds__(256, 2)
void conv_s2_mfma_k(const unsigned short* __restrict__ in,
                    const unsigned short* __restrict__ bhT,
                    const unsigned short* __restrict__ dwT,
                    unsigned short* __restrict__ out, void* __restrict__ skipout_,
                    const float* __restrict__ mean, const float* __restrict__ rstd,
                    const float* __restrict__ gnw, const float* __restrict__ gnb,
                    int H, int W, int OH, int OW, int TX, int TY) {
    __shared__ unsigned short hp[256 * 72];
    __shared__ float rsum[256], rssq[256], sM[32], sR[32];

    int b = blockIdx.x;
    int tx = b % TX; b /= TX;
    int ty = b % TY; int n = b / TY;
    int oy0 = ty * 7, ox0 = tx * 7;

    const int t = threadIdx.x;
    const int lane = t & 63, nt = t >> 6;
    const int colL = lane & 15, q = lane >> 4;
    const int co = nt * 16 + colL;
    const int kq0 = q * 8;

    short8 wr[18], dr[2];
#pragma unroll
    for (int i = 0; i < 18; i++) wr[i] = ((const short8*)bhT)[(i * 4 + nt) * 64 + lane];
    dr[0] = ((const short8*)dwT)[(0 * 4 + nt) * 64 + lane];
    dr[1] = ((const short8*)dwT)[(1 * 4 + nt) * 64 + lane];

    for (int i = t; i < 256 * 72 / 2; i += 256) ((unsigned int*)hp)[i] = 0u;

    const unsigned short* ip = in + (size_t)n * 64 * H * W;
    if constexpr (SELF) {
        IN_STATS_BF(ip, H * W)
    } else {
        if (t < 32) { sM[t] = mean[n * 32 + t]; sR[t] = rstd[n * 32 + t]; }
        __syncthreads();
    }

    for (int i = t; i < 64 * 240; i += 256) {
        int ch = i / 240; int rc = i - ch * 240;
        int r = rc >> 4, c = rc & 15;
        int iy = 2 * oy0 - 1 + r;
        int ix = (c < 8) ? (2 * ox0 + 2 * c) : (2 * ox0 - 1 + 2 * (c - 8));
        if ((unsigned)iy < (unsigned)H && (unsigned)ix < (unsigned)W) {
            float m = sM[ch >> 1], rs = sR[ch >> 1];
            float raw = bf2f(ip[(size_t)ch * H * W + iy * W + ix]);
            float v = fmaxf((raw - m) * rs * gnw[ch] + gnb[ch], 0.f);
            hp[(r * 16 + c) * 72 + ch] = f2bf(v);
        }
    }
    __syncthreads();

    int bs0, bs1, bs2, bs3;
    {
#define BSLOT(dst, mm)                                                          \
        {                                                                       \
            int p_ = (mm) * 16 + colL;                                          \
            int oy_ = p_ >> 3, ox_ = p_ & 7;                                    \
            dst = (ox_ < 7 && oy_ < 7) ? ((2 * oy_) * 16 + ox_) : 0;            \
        }
        BSLOT(bs0, 0) BSLOT(bs1, 1) BSLOT(bs2, 2) BSLOT(bs3, 3)
#undef BSLOT
    }

    f32x4 a0, a1, a2, a3, k0, k1, k2, k3;
    a0 = (f32x4){0.f, 0.f, 0.f, 0.f}; a1 = a0; a2 = a0; a3 = a0;
    k0 = a0; k1 = a0; k2 = a0; k3 = a0;

#pragma unroll
    for (int t9 = 0; t9 < 9; t9++) {
        const int kx = t9 % 3;
        const int toff = (t9 / 3) * 16 + (kx == 0 ? 8 : (kx == 1 ? 0 : 9));
#pragma unroll
        for (int ks = 0; ks < 2; ks++) {
            short8 vb = wr[t9 * 2 + ks];
            int kq = ks * 32 + kq0;
#define TAP(areg, bs)                                                           \
            {                                                                   \
                short8 av = *(const short8*)(hp + ((bs) + toff) * 72 + kq);     \
                areg = __builtin_amdgcn_mfma_f32_16x16x32_bf16(av, vb, areg, 0, 0, 0); \
            }
            TAP(a0, bs0) TAP(a1, bs1) TAP(a2, bs2) TAP(a3, bs3)
#undef TAP
        }
    }
#pragma unroll
    for (int ks = 0; ks < 2; ks++) {
        short8 vb = dr[ks];
        int kq = ks * 32 + kq0;
#define TAP(areg, bs)                                                           \
        {                                                                       \
            short8 av = *(const short8*)(hp + ((bs) + 16) * 72 + kq);           \
            areg = __builtin_amdgcn_mfma_f32_16x16x32_bf16(av, vb, areg, 0, 0, 0); \
        }
        TAP(k0, bs0) TAP(k1, bs1) TAP(k2, bs2) TAP(k3, bs3)
#undef TAP
    }

#define WB(areg, kreg, mm)                                                      \
    _Pragma("unroll")                                                           \
    for (int j = 0; j < 4; j++) {                                               \
        int p_ = (mm) * 16 + q * 4 + j;                                         \
        int oy_ = p_ >> 3, ox_ = p_ & 7;                                        \
        if (ox_ < 7 && oy_ < 7 && oy0 + oy_ < OH && ox0 + ox_ < OW) {           \
            size_t idx = (((size_t)n * 64 + co) * OH + oy0 + oy_) * OW + ox0 + ox_; \
            out[idx] = f2bf(areg[j]);                                           \
            if constexpr (FP32SKIP) ((float*)skipout_)[idx] = kreg[j];          \
            else ((unsigned short*)skipout_)[idx] = f2bf(kreg[j]);              \
        }                                                                       \
    }
    WB(a0, k0, 0) WB(a1, k1, 1) WB(a2, k2, 2) WB(a3, k3, 3)
#undef WB
}

// ======================= 13x13 MFMA conv (r1_c2, self GN, bf16 io) ===========

__global__ __launch_bounds__(256, 2)
void conv13_mfma_k(const unsigned short* __restrict__ in,
                   const unsigned short* __restrict__ bhT,
                   unsigned short* __restrict__ io,
                   const float* __restrict__ gnw, const float* __restrict__ gnb) {
    __shared__ unsigned short hp[256 * 72];
    __shared__ float rsum[256], rssq[256], sM[32], sR[32];
    const int t = threadIdx.x;
    const int n = blockIdx.x;
    const int lane = t & 63;
    const int nt = t >> 6;
    const int colL = lane & 15, q = lane >> 4;
    const int co = nt * 16 + colL;
    const int kq0 = q * 8;

    short8 wr[18];
#pragma unroll
    for (int i = 0; i < 18; i++) wr[i] = ((const short8*)bhT)[(i * 4 + nt) * 64 + lane];

    for (int i = t; i < 256 * 72 / 2; i += 256) ((unsigned int*)hp)[i] = 0u;

    const unsigned short* ip = in + (size_t)n * 64 * 169;
    IN_STATS_BF(ip, 169)

    for (int i = t; i < 64 * 169; i += 256) {
        int ch = i / 169, p = i - ch * 169;
        int y = p / 13, x = p - y * 13;
        float m = sM[ch >> 1], rs = sR[ch >> 1];
        float v = fmaxf((bf2f(ip[i]) - m) * rs * gnw[ch] + gnb[ch], 0.f);
        hp[((y + 1) * 16 + (x + 1)) * 72 + ch] = f2bf(v);
    }
    __syncthreads();

    int hb[11];
#pragma unroll
    for (int m = 0; m < 11; m++) {
        int p = m * 16 + colL;
        int y = p / 13, x = p - y * 13;
        hb[m] = (y + 1) * 16 + (x + 1);
    }
    f32x4 acc[11];
#pragma unroll
    for (int m = 0; m < 11; m++) acc[m] = (f32x4){0.f, 0.f, 0.f, 0.f};

#pragma unroll
    for (int t9 = 0; t9 < 9; t9++) {
        const int toff = (t9 / 3) * 16 + (t9 % 3) - 17;
#pragma unroll
        for (int ks = 0; ks < 2; ks++) {
            short8 vb = wr[t9 * 2 + ks];
            int kq = ks * 32 + kq0;
#pragma unroll
            for (int m = 0; m < 11; m++) {
                short8 a_ = *(const short8*)(hp + (hb[m] + toff) * 72 + kq);
                acc[m] = __builtin_amdgcn_mfma_f32_16x16x32_bf16(a_, vb, acc[m], 0, 0, 0);
            }
        }
    }

    unsigned short* op = io + (size_t)n * 64 * 169 + (size_t)co * 169;
#pragma unroll
    for (int m = 0; m < 11; m++) {
        int p0 = m * 16 + q * 4;
#pragma unroll
        for (int j = 0; j < 4; j++) {
            int p = p0 + j;
            if (p < 169) op[p] = f2bf(bf2f(op[p]) + acc[m][j]);
        }
    }
}

// ======================= ODE MFMA mega-kernel ================================

#define HP_PITCH 72
#define HP_PLANE (100 * HP_PITCH)

#define PVALID(p) ((((p) & 7) < 7) && (((p) >> 3) < 7))
#define PSLOT(p)  (((((p) >> 3) + 1) * 10) + (((p) & 7) + 1))

#define CONV_TAP(areg, hbase)                                                   \
    {                                                                           \
        short8 a_ = *(const short8*)(hp + ((hbase) + toff) * HP_PITCH + kq);    \
        areg = __builtin_amdgcn_mfma_f32_16x16x32_bf16(a_, vb, areg, 0, 0, 0);  \
    }

#define CONV_MFMA(hpsrc, wreg)                                                  \
    a0 = (f32x4){0.f, 0.f, 0.f, 0.f}; a1 = a0; a2 = a0; a3 = a0;                \
    {                                                                           \
        const unsigned short* hp = (hpsrc);                                     \
        __builtin_amdgcn_s_setprio(1);                                          \
        _Pragma("unroll")                                                       \
        for (int t9 = 0; t9 < 9; t9++) {                                        \
            const int toff = (t9 / 3) * 10 + (t9 % 3) - 11;                     \
            _Pragma("unroll")                                                   \
            for (int ks = 0; ks < 2; ks++) {                                    \
                short8 vb = wreg[t9 * 2 + ks];                                  \
                int kq = ks * 32 + kq0;                                         \
                CONV_TAP(a0, h0)                                                \
                CONV_TAP(a1, h1)                                                \
                CONV_TAP(a2, h2)                                                \
                CONV_TAP(a3, h3)                                                \
            }                                                                   \
        }                                                                       \
        __builtin_amdgcn_s_setprio(0);                                          \
    }

#define CONV_MFMA_G(hpsrc, bhT)                                                 \
    a0 = (f32x4){0.f, 0.f, 0.f, 0.f}; a1 = a0; a2 = a0; a3 = a0;                \
    {                                                                           \
        const unsigned short* hp = (hpsrc);                                     \
        const short8* bh_ = (const short8*)(bhT);                               \
        _Pragma("unroll")                                                       \
        for (int t9 = 0; t9 < 9; t9++) {                                        \
            const int toff = (t9 / 3) * 10 + (t9 % 3) - 11;                     \
            _Pragma("unroll")                                                   \
            for (int ks = 0; ks < 2; ks++) {                                    \
                short8 vb = bh_[((t9 * 2 + ks) * 4 + nt) * 64 + lane];          \
                int kq = ks * 32 + kq0;                                         \
                CONV_TAP(a0, h0)                                                \
                CONV_TAP(a1, h1)                                                \
                CONV_TAP(a2, h2)                                                \
                CONV_TAP(a3, h3)                                                \
            }                                                                   \
        }                                                                       \
    }

#define GN_ACCUM(areg, mm)                                                      \
    _Pragma("unroll")                                                           \
    for (int j = 0; j < 4; j++) {                                               \
        int p_ = (mm) * 16 + q * 4 + j;                                         \
        if (PVALID(p_)) { float x_ = areg[j]; s += x_; s2 += x_ * x_; }         \
    }

#define GN_STORE(dst, areg, mm)                                                 \
    _Pragma("unroll")                                                           \
    for (int j = 0; j < 4; j++) {                                               \
        int p_ = (mm) * 16 + q * 4 + j;                                         \
        if (PVALID(p_)) {                                                       \
            float y_ = fmaxf(areg[j] * sc + sh, 0.f);                           \
            (dst)[PSLOT(p_) * HP_PITCH + co] = f2bf(y_);                        \
        }                                                                       \
    }

#define RK4_REG(areg, zm, zam, um)                                              \
    {                                                                           \
        f32x4 kv = areg + um;                                                   \
        zam = (e == 0) ? (zm + ck * kv) : (zam + ck * kv);                      \
        if (e < 3) um = zm + cu * kv;                                           \
    }

__global__ __launch_bounds__(256, 2)
void ode_mfma_k(const unsigned short* __restrict__ u7raw, const float* __restrict__ z7,
                const float* __restrict__ pgw, const float* __restrict__ pgb,
                const unsigned short* __restrict__ wr2h,
                const unsigned short* __restrict__ wb1h,
                const unsigned short* __restrict__ wb2h,
                const float* __restrict__ g1w, const float* __restrict__ g1b,
                const float* __restrict__ g2w, const float* __restrict__ g2b,
                const float* __restrict__ fgw, const float* __restrict__ fgb,
                const float* __restrict__ fcw, const float* __restrict__ fcb,
                float* __restrict__ out) {
    __shared__ unsigned short hp1[HP_PLANE], hp2[HP_PLANE];
    __shared__ float rsum[256], rssq[256], sM[32], sR[32];
    __shared__ float pooled[64];

    const int t = threadIdx.x;
    const int n = blockIdx.x;
    const int lane = t & 63;
    const int nt = t >> 6;
    const int colL = lane & 15, q = lane >> 4;
    const int co = nt * 16 + colL;

    const float g1wv = g1w[co], g1bv = g1b[co];
    const float g2wv = g2w[co], g2bv = g2b[co];

    const int h0 = PSLOT(colL);
    const int h1 = PSLOT(16 + colL);
    const int h2 = PSLOT(32 + colL);
    const int h3 = PSLOT(48 + colL);
    const int kq0 = q * 8;

    short8 w1r[18], w2r[18];
#pragma unroll
    for (int i = 0; i < 18; i++) {
        int fidx = (i * 4 + nt) * 64 + lane;
        w1r[i] = ((const short8*)wb1h)[fidx];
        w2r[i] = ((const short8*)wb2h)[fidx];
    }

    for (int i = t; i < HP_PLANE; i += 256) { hp1[i] = 0; hp2[i] = 0; }

    const unsigned short* up = u7raw + (size_t)n * 3136;
    IN_STATS_BF(up, 49)

    for (int i = t; i < 3136; i += 256) {
        int ch = i / 49, r = i - ch * 49;
        int y = r / 7, x = r - y * 7;
        float m = sM[ch >> 1], rs = sR[ch >> 1];
        float v = fmaxf((bf2f(up[i]) - m) * rs * pgw[ch] + pgb[ch], 0.f);
        hp1[((y + 1) * 10 + (x + 1)) * HP_PITCH + ch] = f2bf(v);
    }
    __syncthreads();

    f32x4 zr0, zr1, zr2, zr3;
    f32x4 za0, za1, za2, za3;
    f32x4 ur0, ur1, ur2, ur3;
    {
        f32x4 a0, a1, a2, a3;
        CONV_MFMA_G(hp1, wr2h)
        const float* zb = z7 + (size_t)n * 3136 + (size_t)co * 49;
#define INITZ(zm, areg, mm)                                                     \
        _Pragma("unroll")                                                       \
        for (int j = 0; j < 4; j++) {                                           \
            int p_ = (mm) * 16 + q * 4 + j;                                     \
            zm[j] = PVALID(p_) ? (areg[j] + zb[(p_ >> 3) * 7 + (p_ & 7)]) : 0.f;\
        }
        INITZ(zr0, a0, 0) INITZ(zr1, a1, 1) INITZ(zr2, a2, 2) INITZ(zr3, a3, 3)
#undef INITZ
    }
    ur0 = zr0; ur1 = zr1; ur2 = zr2; ur3 = zr3;
    __syncthreads();

    const float dt = 0.5f;

#pragma unroll 1
    for (int step = 0; step < 12; step++) {
#pragma unroll 1
        for (int e = 0; e < 4; e++) {
            const float ck = (e == 0 || e == 3) ? dt / 6.f : dt / 3.f;
            const float cu = (e == 2) ? dt : 0.5f * dt;

            {
                float s = 0.f, s2 = 0.f;
                GN_ACCUM(ur0, 0) GN_ACCUM(ur1, 1) GN_ACCUM(ur2, 2) GN_ACCUM(ur3, 3)
                s += __shfl_xor(s, 16); s2 += __shfl_xor(s2, 16);
                s += __shfl_xor(s, 32); s2 += __shfl_xor(s2, 32);
                float mu = s * (1.f / 49.f);
                float r = rsqrtf(s2 * (1.f / 49.f) - mu * mu + 1e-5f);
                float sc = r * g1wv, sh = g1bv - mu * sc;
                GN_STORE(hp1, ur0, 0) GN_STORE(hp1, ur1, 1)
                GN_STORE(hp1, ur2, 2) GN_STORE(hp1, ur3, 3)
            }
            __syncthreads();   // B1

            {
                f32x4 a0, a1, a2, a3;
                CONV_MFMA(hp1, w1r)

                float s = 0.f, s2 = 0.f;
                GN_ACCUM(a0, 0) GN_ACCUM(a1, 1) GN_ACCUM(a2, 2) GN_ACCUM(a3, 3)
                s += __shfl_xor(s, 16); s2 += __shfl_xor(s2, 16);
                s += __shfl_xor(s, 32); s2 += __shfl_xor(s2, 32);
                float mu = s * (1.f / 49.f);
                float r = rsqrtf(s2 * (1.f / 49.f) - mu * mu + 1e-5f);
                float sc = r * g2wv, sh = g2bv - mu * sc;
                GN_STORE(hp2, a0, 0) GN_STORE(hp2, a1, 1)
                GN_STORE(hp2, a2, 2) GN_STORE(hp2, a3, 3)
            }
            __syncthreads();   // B2

            {
                f32x4 a0, a1, a2, a3;
                CONV_MFMA(hp2, w2r)

                RK4_REG(a0, zr0, za0, ur0) RK4_REG(a1, zr1, za1, ur1)
                RK4_REG(a2, zr2, za2, ur2) RK4_REG(a3, zr3, za3, ur3)
                if (e == 3) {
                    zr0 = za0; zr1 = za1; zr2 = za2; zr3 = za3;
                    ur0 = zr0; ur1 = zr1; ur2 = zr2; ur3 = zr3;
                }
            }
        }
    }

    {
        float s = 0.f, s2 = 0.f;
        GN_ACCUM(zr0, 0) GN_ACCUM(zr1, 1) GN_ACCUM(zr2, 2) GN_ACCUM(zr3, 3)
        s += __shfl_xor(s, 16); s2 += __shfl_xor(s2, 16);
        s += __shfl_xor(s, 32); s2 += __shfl_xor(s2, 32);
        s += __shfl_xor(s, 1);  s2 += __shfl_xor(s2, 1);
        float mu = s * (1.f / 98.f);
        float r = rsqrtf(s2 * (1.f / 98.f) - mu * mu + 1e-5f);
        float sc = r * fgw[co], sh = fgb[co] - mu * sc;
        float ps = 0.f;
#pragma unroll
        for (int mm = 0; mm < 4; mm++) {
            f32x4 zz = (mm == 0) ? zr0 : (mm == 1) ? zr1 : (mm == 2) ? zr2 : zr3;
#pragma unroll
            for (int j = 0; j < 4; j++) {
                int p_ = mm * 16 + q * 4 + j;
                if (PVALID(p_)) ps += fmaxf(zz[j] * sc + sh, 0.f);
            }
        }
        ps += __shfl_xor(ps, 16);
        ps += __shfl_xor(ps, 32);
        if (q == 0) pooled[co] = ps * (1.f / 49.f);
    }
    __syncthreads();
    if (t < 10) {
        float a = fcb[t];
#pragma unroll
        for (int k = 0; k < 64; k++) a += pooled[k] * fcw[t * 64 + k];
        out[(size_t)n * 10 + t] = a;
    }
}

static inline int nblk(long long total) { return (int)((total + TPB - 1) / TPB); }

extern "C" void kernel_launch(void* const* d_in, const int* in_sizes, int n_in,
                              void* d_out, int out_size, void* d_ws, size_t ws_size,
                              hipStream_t stream) {
    const float* x       = (const float*)d_in[0];
    const float* conv1_w = (const float*)d_in[1];
    const float* conv1_b = (const float*)d_in[2];
    const float* r1_g1w  = (const float*)d_in[3];
    const float* r1_g1b  = (const float*)d_in[4];
    const float* r1_c1w  = (const float*)d_in[5];
    const float* r1_g2w  = (const float*)d_in[6];
    const float* r1_g2b  = (const float*)d_in[7];
    const float* r1_c2w  = (const float*)d_in[8];
    const float* r1_dw   = (const float*)d_in[9];
    const float* r2_g1w  = (const float*)d_in[10];
    const float* r2_g1b  = (const float*)d_in[11];
    const float* r2_c1w  = (const float*)d_in[12];
    const float* r2_g2w  = (const float*)d_in[13];
    const float* r2_g2b  = (const float*)d_in[14];
    const float* r2_c2w  = (const float*)d_in[15];
    const float* r2_dw   = (const float*)d_in[16];
    const float* o_g1w   = (const float*)d_in[17];
    const float* o_g1b   = (const float*)d_in[18];
    const float* o_c1w   = (const float*)d_in[19];
    const float* o_g2w   = (const float*)d_in[20];
    const float* o_g2b   = (const float*)d_in[21];
    const float* o_c2w   = (const float*)d_in[22];
    const float* fin_gw  = (const float*)d_in[23];
    const float* fin_gb  = (const float*)d_in[24];
    const float* fc_w    = (const float*)d_in[25];
    const float* fc_b    = (const float*)d_in[26];
    float* out = (float*)d_out;

    const long long SZ26 = 512LL * 64 * 26 * 26;
    const long long SZ13 = 512LL * 64 * 13 * 13;
    const long long SZ7  = 512LL * 64 * 7 * 7;
    const long long WBS  = 9 * 2 * 4 * 64 * 8;
    const long long WBS1 = 2 * 4 * 64 * 8;

    // bf16 intermediates (pre-GN tensors); Z7 stays fp32 (raw ODE state)
    unsigned short* B26 = (unsigned short*)d_ws;
    unsigned short* A13 = B26 + SZ26;
    unsigned short* B13 = A13 + SZ13;
    unsigned short* U7  = B13 + SZ13;
    float* Z7   = (float*)(U7 + SZ7 + (SZ7 & 1));
    float* MEAN = Z7 + SZ7;
    float* RSTD = MEAN + 512 * 32;
    unsigned short* WTAB  = (unsigned short*)(RSTD + 512 * 32);
    unsigned short* WB1h  = WTAB;               // o_c1w
    unsigned short* WB2h  = WTAB + WBS;         // o_c2w
    unsigned short* WB13h = WTAB + 2 * WBS;     // r1_c2w
    unsigned short* WR2h  = WTAB + 3 * WBS;     // r2_c2w
    unsigned short* WR11h = WTAB + 4 * WBS;     // r1_c1w
    unsigned short* WR21h = WTAB + 5 * WBS;     // r2_c1w
    unsigned short* WD1h  = WTAB + 6 * WBS;     // r1_dw
    unsigned short* WD2h  = WTAB + 6 * WBS + WBS1; // r2_dw

    wsplit_all_k<<<nblk(6 * WBS + 2 * WBS1), TPB, 0, stream>>>(
        o_c1w, o_c2w, r1_c2w, r2_c2w, r1_c1w, r2_c1w, r1_dw, r2_dw, WTAB);

    conv1_k<<<nblk(SZ26), TPB, 0, stream>>>(x, conv1_w, conv1_b, B26);

    // ---- residual block 1: 26x26 -> 13x13 (4 blocks/image -> shared stats) --
    gn_stats_bf_k<<<nblk(512LL * 32 * 64), TPB, 0, stream>>>(B26, MEAN, RSTD, 512, 64, 676, 32);
    conv_s2_mfma_k<false, false><<<512 * 4, 256, 0, stream>>>(B26, WR11h, WD1h, A13, B13,
                                                              MEAN, RSTD, r1_g1w, r1_g1b,
                                                              26, 26, 13, 13, 2, 2);
    conv13_mfma_k<<<512, 256, 0, stream>>>(A13, WB13h, B13, r1_g2w, r1_g2b);

    // ---- residual block 2: 13x13 -> 7x7 (1 block/image -> self stats) -------
    // skipout = Z7 in fp32 (ODE initial state)
    conv_s2_mfma_k<true, true><<<512, 256, 0, stream>>>(B13, WR21h, WD2h, U7, Z7,
                                                        nullptr, nullptr, r2_g1w, r2_g1b,
                                                        13, 13, 7, 7, 1, 1);

    // ---- fused: GN + r2_c2 conv + skip + ODE RK4 + final GN + pool + FC ----
    ode_mfma_k<<<512, 256, 0, stream>>>(U7, Z7, r2_g2w, r2_g2b,
                                        WR2h, WB1h, WB2h,
                                        o_g1w, o_g1b, o_g2w, o_g2b,
                                        fin_gw, fin_gb, fc_w, fc_b, out);
}

// Round 18
// 534.969 us; speedup vs baseline: 1.2611x; 1.0871x over previous
//
#include <hip/hip_runtime.h>
#include <hip/hip_bf16.h>

#define TPB 256

typedef __attribute__((ext_vector_type(8))) short short8;
typedef __attribute__((ext_vector_type(4))) float f32x4;

__device__ __forceinline__ unsigned short f2bf(float x) {
    union { float f; unsigned int u; } c; c.f = x;
    unsigned int u = c.u;
    unsigned int r = (u + 0x7fffu + ((u >> 16) & 1u)) >> 16;
    return (unsigned short)r;
}
__device__ __forceinline__ float bf2f(unsigned short h) {
    union { unsigned int u; float f; } c; c.u = ((unsigned int)h) << 16;
    return c.f;
}

// ---- in-block GN stats from a bf16 tensor (C=64, G=32) -> sM[32], sR[32] ----
#define IN_STATS_BF(Xp, HW)                                                     \
    {                                                                           \
        int ch_ = t >> 2, sg_ = t & 3;                                          \
        float s_ = 0.f, s2_ = 0.f;                                              \
        for (int i_ = sg_; i_ < (HW); i_ += 4) {                                \
            float v_ = bf2f((Xp)[(size_t)ch_ * (HW) + i_]);                     \
            s_ += v_; s2_ += v_ * v_;                                           \
        }                                                                       \
        rsum[t] = s_; rssq[t] = s2_;                                            \
        __syncthreads();                                                        \
        if (t < 32) {                                                           \
            float S = 0.f, S2 = 0.f;                                            \
            _Pragma("unroll")                                                   \
            for (int k_ = 0; k_ < 8; k_++) {                                    \
                int tt_ = (2 * t + (k_ & 1)) * 4 + (k_ >> 1);                   \
                S += rsum[tt_]; S2 += rssq[tt_];                                \
            }                                                                   \
            float mu_ = S / (2.f * (HW));                                       \
            sM[t] = mu_;                                                        \
            sR[t] = rsqrtf(S2 / (2.f * (HW)) - mu_ * mu_ + 1e-5f);              \
        }                                                                       \
        __syncthreads();                                                        \
    }

// ======================= conv1 + GN stats (fused, block per image) ===========
// Thread = (ch = t>>2, quarter = t&3): computes 169 of the 676 outputs for its
// channel, accumulating stats on the bf16-ROUNDED values (bit-consistent with
// the old gn_stats_bf pass over the stored tensor).

__global__ __launch_bounds__(256, 2)
void conv1_stats_k(const float* __restrict__ x, const float* __restrict__ w,
                   const float* __restrict__ b, unsigned short* __restrict__ out,
                   float* __restrict__ mean, float* __restrict__ rstd) {
    __shared__ float xs[784];
    __shared__ float rsum[256], rssq[256];
    const int n = blockIdx.x, t = threadIdx.x;

    for (int i = t; i < 784; i += 256) xs[i] = x[(size_t)n * 784 + i];
    __syncthreads();

    const int ch = t >> 2, sg = t & 3;
    float wv[9];
#pragma unroll
    for (int k = 0; k < 9; k++) wv[k] = w[ch * 9 + k];
    const float bv = b[ch];
    unsigned short* op = out + (size_t)n * 64 * 676 + (size_t)ch * 676;

    float s = 0.f, s2 = 0.f;
    for (int p = sg; p < 676; p += 4) {
        int oy = p / 26, ox = p - oy * 26;
        const float* xp = xs + oy * 28 + ox;
        float acc = bv;
#pragma unroll
        for (int ky = 0; ky < 3; ky++)
#pragma unroll
            for (int kx = 0; kx < 3; kx++)
                acc = fmaf(xp[ky * 28 + kx], wv[ky * 3 + kx], acc);
        unsigned short h = f2bf(acc);
        op[p] = h;
        float ar = bf2f(h);
        s += ar; s2 += ar * ar;
    }
    rsum[t] = s; rssq[t] = s2;
    __syncthreads();
    if (t < 32) {
        float S = 0.f, S2 = 0.f;
#pragma unroll
        for (int k = 0; k < 8; k++) {
            int tt = (2 * t + (k & 1)) * 4 + (k >> 1);
            S += rsum[tt]; S2 += rssq[tt];
        }
        float mu = S / (2.f * 676.f);
        mean[n * 32 + t] = mu;
        rstd[n * 32 + t] = rsqrtf(S2 / (2.f * 676.f) - mu * mu + 1e-5f);
    }
}

// ======================= combined weight prep ================================

__global__ void wsplit_all_k(const float* __restrict__ w0, const float* __restrict__ w1,
                             const float* __restrict__ w2, const float* __restrict__ w3,
                             const float* __restrict__ w4, const float* __restrict__ w5,
                             const float* __restrict__ d0, const float* __restrict__ d1,
                             unsigned short* __restrict__ dst) {
    const int WBS = 9 * 2 * 4 * 64 * 8, WBS1 = 2 * 4 * 64 * 8;
    int i = blockIdx.x * TPB + threadIdx.x;
    if (i < 6 * WBS) {
        int tbl = i / WBS; int r = i - tbl * WBS;
        const float* w = (tbl == 0) ? w0 : (tbl == 1) ? w1 : (tbl == 2) ? w2
                       : (tbl == 3) ? w3 : (tbl == 4) ? w4 : w5;
        int j = r & 7, l = (r >> 3) & 63, nt = (r >> 9) & 3, ks = (r >> 11) & 1, tt = r >> 12;
        int co = nt * 16 + (l & 15);
        int ci = ks * 32 + (l >> 4) * 8 + j;
        dst[i] = f2bf(w[(co * 64 + ci) * 9 + tt]);
    } else {
        int r = i - 6 * WBS;
        if (r >= 2 * WBS1) return;
        int tbl = r / WBS1; r -= tbl * WBS1;
        const float* w = tbl ? d1 : d0;
        int j = r & 7, l = (r >> 3) & 63, nt = (r >> 9) & 3, ks = (r >> 11) & 1;
        int co = nt * 16 + (l & 15);
        int ci = ks * 32 + (l >> 4) * 8 + j;
        dst[6 * WBS + tbl * WBS1 + r] = f2bf(w[co * 64 + ci]);
    }
}

// ======================= stride-2 MFMA conv (+GN, +1x1 skip) =================

template<bool SELF, bool FP32SKIP>
__global__ __launch_bounds__(256, 2)
void conv_s2_mfma_k(const unsigned short* __restrict__ in,
                    const unsigned short* __restrict__ bhT,
                    const unsigned short* __restrict__ dwT,
                    unsigned short* __restrict__ out, void* __restrict__ skipout_,
                    const float* __restrict__ mean, const float* __restrict__ rstd,
                    const float* __restrict__ gnw, const float* __restrict__ gnb,
                    int H, int W, int OH, int OW, int TX, int TY) {
    __shared__ unsigned short hp[256 * 72];
    __shared__ float rsum[256], rssq[256], sM[32], sR[32];

    int b = blockIdx.x;
    int tx = b % TX; b /= TX;
    int ty = b % TY; int n = b / TY;
    int oy0 = ty * 7, ox0 = tx * 7;

    const int t = threadIdx.x;
    const int lane = t & 63, nt = t >> 6;
    const int colL = lane & 15, q = lane >> 4;
    const int co = nt * 16 + colL;
    const int kq0 = q * 8;

    short8 wr[18], dr[2];
#pragma unroll
    for (int i = 0; i < 18; i++) wr[i] = ((const short8*)bhT)[(i * 4 + nt) * 64 + lane];
    dr[0] = ((const short8*)dwT)[(0 * 4 + nt) * 64 + lane];
    dr[1] = ((const short8*)dwT)[(1 * 4 + nt) * 64 + lane];

    for (int i = t; i < 256 * 72 / 2; i += 256) ((unsigned int*)hp)[i] = 0u;

    const unsigned short* ip = in + (size_t)n * 64 * H * W;
    if constexpr (SELF) {
        IN_STATS_BF(ip, H * W)
    } else {
        if (t < 32) { sM[t] = mean[n * 32 + t]; sR[t] = rstd[n * 32 + t]; }
        __syncthreads();
    }

    for (int i = t; i < 64 * 240; i += 256) {
        int ch = i / 240; int rc = i - ch * 240;
        int r = rc >> 4, c = rc & 15;
        int iy = 2 * oy0 - 1 + r;
        int ix = (c < 8) ? (2 * ox0 + 2 * c) : (2 * ox0 - 1 + 2 * (c - 8));
        if ((unsigned)iy < (unsigned)H && (unsigned)ix < (unsigned)W) {
            float m = sM[ch >> 1], rs = sR[ch >> 1];
            float raw = bf2f(ip[(size_t)ch * H * W + iy * W + ix]);
            float v = fmaxf((raw - m) * rs * gnw[ch] + gnb[ch], 0.f);
            hp[(r * 16 + c) * 72 + ch] = f2bf(v);
        }
    }
    __syncthreads();

    int bs0, bs1, bs2, bs3;
    {
#define BSLOT(dst, mm)                                                          \
        {                                                                       \
            int p_ = (mm) * 16 + colL;                                          \
            int oy_ = p_ >> 3, ox_ = p_ & 7;                                    \
            dst = (ox_ < 7 && oy_ < 7) ? ((2 * oy_) * 16 + ox_) : 0;            \
        }
        BSLOT(bs0, 0) BSLOT(bs1, 1) BSLOT(bs2, 2) BSLOT(bs3, 3)
#undef BSLOT
    }

    f32x4 a0, a1, a2, a3, k0, k1, k2, k3;
    a0 = (f32x4){0.f, 0.f, 0.f, 0.f}; a1 = a0; a2 = a0; a3 = a0;
    k0 = a0; k1 = a0; k2 = a0; k3 = a0;

#pragma unroll
    for (int t9 = 0; t9 < 9; t9++) {
        const int kx = t9 % 3;
        const int toff = (t9 / 3) * 16 + (kx == 0 ? 8 : (kx == 1 ? 0 : 9));
#pragma unroll
        for (int ks = 0; ks < 2; ks++) {
            short8 vb = wr[t9 * 2 + ks];
            int kq = ks * 32 + kq0;
#define TAP(areg, bs)                                                           \
            {                                                                   \
                short8 av = *(const short8*)(hp + ((bs) + toff) * 72 + kq);     \
                areg = __builtin_amdgcn_mfma_f32_16x16x32_bf16(av, vb, areg, 0, 0, 0); \
            }
            TAP(a0, bs0) TAP(a1, bs1) TAP(a2, bs2) TAP(a3, bs3)
#undef TAP
        }
    }
#pragma unroll
    for (int ks = 0; ks < 2; ks++) {
        short8 vb = dr[ks];
        int kq = ks * 32 + kq0;
#define TAP(areg, bs)                                                           \
        {                                                                       \
            short8 av = *(const short8*)(hp + ((bs) + 16) * 72 + kq);           \
            areg = __builtin_amdgcn_mfma_f32_16x16x32_bf16(av, vb, areg, 0, 0, 0); \
        }
        TAP(k0, bs0) TAP(k1, bs1) TAP(k2, bs2) TAP(k3, bs3)
#undef TAP
    }

#define WB(areg, kreg, mm)                                                      \
    _Pragma("unroll")                                                           \
    for (int j = 0; j < 4; j++) {                                               \
        int p_ = (mm) * 16 + q * 4 + j;                                         \
        int oy_ = p_ >> 3, ox_ = p_ & 7;                                        \
        if (ox_ < 7 && oy_ < 7 && oy0 + oy_ < OH && ox0 + ox_ < OW) {           \
            size_t idx = (((size_t)n * 64 + co) * OH + oy0 + oy_) * OW + ox0 + ox_; \
            out[idx] = f2bf(areg[j]);                                           \
            if constexpr (FP32SKIP) ((float*)skipout_)[idx] = kreg[j];          \
            else ((unsigned short*)skipout_)[idx] = f2bf(kreg[j]);              \
        }                                                                       \
    }
    WB(a0, k0, 0) WB(a1, k1, 1) WB(a2, k2, 2) WB(a3, k3, 3)
#undef WB
}

// ======================= 13x13 MFMA conv (r1_c2, self GN, bf16 io) ===========

__global__ __launch_bounds__(256, 2)
void conv13_mfma_k(const unsigned short* __restrict__ in,
                   const unsigned short* __restrict__ bhT,
                   unsigned short* __restrict__ io,
                   const float* __restrict__ gnw, const float* __restrict__ gnb) {
    __shared__ unsigned short hp[256 * 72];
    __shared__ float rsum[256], rssq[256], sM[32], sR[32];
    const int t = threadIdx.x;
    const int n = blockIdx.x;
    const int lane = t & 63;
    const int nt = t >> 6;
    const int colL = lane & 15, q = lane >> 4;
    const int co = nt * 16 + colL;
    const int kq0 = q * 8;

    short8 wr[18];
#pragma unroll
    for (int i = 0; i < 18; i++) wr[i] = ((const short8*)bhT)[(i * 4 + nt) * 64 + lane];

    for (int i = t; i < 256 * 72 / 2; i += 256) ((unsigned int*)hp)[i] = 0u;

    const unsigned short* ip = in + (size_t)n * 64 * 169;
    IN_STATS_BF(ip, 169)

    for (int i = t; i < 64 * 169; i += 256) {
        int ch = i / 169, p = i - ch * 169;
        int y = p / 13, x = p - y * 13;
        float m = sM[ch >> 1], rs = sR[ch >> 1];
        float v = fmaxf((bf2f(ip[i]) - m) * rs * gnw[ch] + gnb[ch], 0.f);
        hp[((y + 1) * 16 + (x + 1)) * 72 + ch] = f2bf(v);
    }
    __syncthreads();

    int hb[11];
#pragma unroll
    for (int m = 0; m < 11; m++) {
        int p = m * 16 + colL;
        int y = p / 13, x = p - y * 13;
        hb[m] = (y + 1) * 16 + (x + 1);
    }
    f32x4 acc[11];
#pragma unroll
    for (int m = 0; m < 11; m++) acc[m] = (f32x4){0.f, 0.f, 0.f, 0.f};

#pragma unroll
    for (int t9 = 0; t9 < 9; t9++) {
        const int toff = (t9 / 3) * 16 + (t9 % 3) - 17;
#pragma unroll
        for (int ks = 0; ks < 2; ks++) {
            short8 vb = wr[t9 * 2 + ks];
            int kq = ks * 32 + kq0;
#pragma unroll
            for (int m = 0; m < 11; m++) {
                short8 a_ = *(const short8*)(hp + (hb[m] + toff) * 72 + kq);
                acc[m] = __builtin_amdgcn_mfma_f32_16x16x32_bf16(a_, vb, acc[m], 0, 0, 0);
            }
        }
    }

    unsigned short* op = io + (size_t)n * 64 * 169 + (size_t)co * 169;
#pragma unroll
    for (int m = 0; m < 11; m++) {
        int p0 = m * 16 + q * 4;
#pragma unroll
        for (int j = 0; j < 4; j++) {
            int p = p0 + j;
            if (p < 169) op[p] = f2bf(bf2f(op[p]) + acc[m][j]);
        }
    }
}

// ======================= ODE MFMA mega-kernel ================================

#define HP_PITCH 72
#define HP_PLANE (100 * HP_PITCH)

#define PVALID(p) ((((p) & 7) < 7) && (((p) >> 3) < 7))
#define PSLOT(p)  (((((p) >> 3) + 1) * 10) + (((p) & 7) + 1))

#define CONV_TAP(areg, hbase)                                                   \
    {                                                                           \
        short8 a_ = *(const short8*)(hp + ((hbase) + toff) * HP_PITCH + kq);    \
        areg = __builtin_amdgcn_mfma_f32_16x16x32_bf16(a_, vb, areg, 0, 0, 0);  \
    }

#define CONV_MFMA(hpsrc, wreg)                                                  \
    a0 = (f32x4){0.f, 0.f, 0.f, 0.f}; a1 = a0; a2 = a0; a3 = a0;                \
    {                                                                           \
        const unsigned short* hp = (hpsrc);                                     \
        __builtin_amdgcn_s_setprio(1);                                          \
        _Pragma("unroll")                                                       \
        for (int t9 = 0; t9 < 9; t9++) {                                        \
            const int toff = (t9 / 3) * 10 + (t9 % 3) - 11;                     \
            _Pragma("unroll")                                                   \
            for (int ks = 0; ks < 2; ks++) {                                    \
                short8 vb = wreg[t9 * 2 + ks];                                  \
                int kq = ks * 32 + kq0;                                         \
                CONV_TAP(a0, h0)                                                \
                CONV_TAP(a1, h1)                                                \
                CONV_TAP(a2, h2)                                                \
                CONV_TAP(a3, h3)                                                \
            }                                                                   \
        }                                                                       \
        __builtin_amdgcn_s_setprio(0);                                          \
    }

#define CONV_MFMA_G(hpsrc, bhT)                                                 \
    a0 = (f32x4){0.f, 0.f, 0.f, 0.f}; a1 = a0; a2 = a0; a3 = a0;                \
    {                                                                           \
        const unsigned short* hp = (hpsrc);                                     \
        const short8* bh_ = (const short8*)(bhT);                               \
        _Pragma("unroll")                                                       \
        for (int t9 = 0; t9 < 9; t9++) {                                        \
            const int toff = (t9 / 3) * 10 + (t9 % 3) - 11;                     \
            _Pragma("unroll")                                                   \
            for (int ks = 0; ks < 2; ks++) {                                    \
                short8 vb = bh_[((t9 * 2 + ks) * 4 + nt) * 64 + lane];          \
                int kq = ks * 32 + kq0;                                         \
                CONV_TAP(a0, h0)                                                \
                CONV_TAP(a1, h1)                                                \
                CONV_TAP(a2, h2)                                                \
                CONV_TAP(a3, h3)                                                \
            }                                                                   \
        }                                                                       \
    }

#define GN_ACCUM(areg, mm)                                                      \
    _Pragma("unroll")                                                           \
    for (int j = 0; j < 4; j++) {                                               \
        int p_ = (mm) * 16 + q * 4 + j;                                         \
        if (PVALID(p_)) { float x_ = areg[j]; s += x_; s2 += x_ * x_; }         \
    }

#define GN_STORE(dst, areg, mm)                                                 \
    _Pragma("unroll")                                                           \
    for (int j = 0; j < 4; j++) {                                               \
        int p_ = (mm) * 16 + q * 4 + j;                                         \
        if (PVALID(p_)) {                                                       \
            float y_ = fmaxf(areg[j] * sc + sh, 0.f);                           \
            (dst)[PSLOT(p_) * HP_PITCH + co] = f2bf(y_);                        \
        }                                                                       \
    }

#define RK4_REG(areg, zm, zam, um)                                              \
    {                                                                           \
        f32x4 kv = areg + um;                                                   \
        zam = (e == 0) ? (zm + ck * kv) : (zam + ck * kv);                      \
        if (e < 3) um = zm + cu * kv;                                           \
    }

__global__ __launch_bounds__(256, 2)
void ode_mfma_k(const unsigned short* __restrict__ u7raw, const float* __restrict__ z7,
                const float* __restrict__ pgw, const float* __restrict__ pgb,
                const unsigned short* __restrict__ wr2h,
                const unsigned short* __restrict__ wb1h,
                const unsigned short* __restrict__ wb2h,
                const float* __restrict__ g1w, const float* __restrict__ g1b,
                const float* __restrict__ g2w, const float* __restrict__ g2b,
                const float* __restrict__ fgw, const float* __restrict__ fgb,
                const float* __restrict__ fcw, const float* __restrict__ fcb,
                float* __restrict__ out) {
    __shared__ unsigned short hp1[HP_PLANE], hp2[HP_PLANE];
    __shared__ float rsum[256], rssq[256], sM[32], sR[32];
    __shared__ float pooled[64];

    const int t = threadIdx.x;
    const int n = blockIdx.x;
    const int lane = t & 63;
    const int nt = t >> 6;
    const int colL = lane & 15, q = lane >> 4;
    const int co = nt * 16 + colL;

    const float g1wv = g1w[co], g1bv = g1b[co];
    const float g2wv = g2w[co], g2bv = g2b[co];

    const int h0 = PSLOT(colL);
    const int h1 = PSLOT(16 + colL);
    const int h2 = PSLOT(32 + colL);
    const int h3 = PSLOT(48 + colL);
    const int kq0 = q * 8;

    short8 w1r[18], w2r[18];
#pragma unroll
    for (int i = 0; i < 18; i++) {
        int fidx = (i * 4 + nt) * 64 + lane;
        w1r[i] = ((const short8*)wb1h)[fidx];
        w2r[i] = ((const short8*)wb2h)[fidx];
    }

    for (int i = t; i < HP_PLANE; i += 256) { hp1[i] = 0; hp2[i] = 0; }

    const unsigned short* up = u7raw + (size_t)n * 3136;
    IN_STATS_BF(up, 49)

    for (int i = t; i < 3136; i += 256) {
        int ch = i / 49, r = i - ch * 49;
        int y = r / 7, x = r - y * 7;
        float m = sM[ch >> 1], rs = sR[ch >> 1];
        float v = fmaxf((bf2f(up[i]) - m) * rs * pgw[ch] + pgb[ch], 0.f);
        hp1[((y + 1) * 10 + (x + 1)) * HP_PITCH + ch] = f2bf(v);
    }
    __syncthreads();

    f32x4 zr0, zr1, zr2, zr3;
    f32x4 za0, za1, za2, za3;
    f32x4 ur0, ur1, ur2, ur3;
    {
        f32x4 a0, a1, a2, a3;
        CONV_MFMA_G(hp1, wr2h)
        const float* zb = z7 + (size_t)n * 3136 + (size_t)co * 49;
#define INITZ(zm, areg, mm)                                                     \
        _Pragma("unroll")                                                       \
        for (int j = 0; j < 4; j++) {                                           \
            int p_ = (mm) * 16 + q * 4 + j;                                     \
            zm[j] = PVALID(p_) ? (areg[j] + zb[(p_ >> 3) * 7 + (p_ & 7)]) : 0.f;\
        }
        INITZ(zr0, a0, 0) INITZ(zr1, a1, 1) INITZ(zr2, a2, 2) INITZ(zr3, a3, 3)
#undef INITZ
    }
    ur0 = zr0; ur1 = zr1; ur2 = zr2; ur3 = zr3;
    __syncthreads();

    const float dt = 0.5f;

#pragma unroll 1
    for (int step = 0; step < 12; step++) {
#pragma unroll 1
        for (int e = 0; e < 4; e++) {
            const float ck = (e == 0 || e == 3) ? dt / 6.f : dt / 3.f;
            const float cu = (e == 2) ? dt : 0.5f * dt;

            {
                float s = 0.f, s2 = 0.f;
                GN_ACCUM(ur0, 0) GN_ACCUM(ur1, 1) GN_ACCUM(ur2, 2) GN_ACCUM(ur3, 3)
                s += __shfl_xor(s, 16); s2 += __shfl_xor(s2, 16);
                s += __shfl_xor(s, 32); s2 += __shfl_xor(s2, 32);
                float mu = s * (1.f / 49.f);
                float r = rsqrtf(s2 * (1.f / 49.f) - mu * mu + 1e-5f);
                float sc = r * g1wv, sh = g1bv - mu * sc;
                GN_STORE(hp1, ur0, 0) GN_STORE(hp1, ur1, 1)
                GN_STORE(hp1, ur2, 2) GN_STORE(hp1, ur3, 3)
            }
            __syncthreads();   // B1

            {
                f32x4 a0, a1, a2, a3;
                CONV_MFMA(hp1, w1r)

                float s = 0.f, s2 = 0.f;
                GN_ACCUM(a0, 0) GN_ACCUM(a1, 1) GN_ACCUM(a2, 2) GN_ACCUM(a3, 3)
                s += __shfl_xor(s, 16); s2 += __shfl_xor(s2, 16);
                s += __shfl_xor(s, 32); s2 += __shfl_xor(s2, 32);
                float mu = s * (1.f / 49.f);
                float r = rsqrtf(s2 * (1.f / 49.f) - mu * mu + 1e-5f);
                float sc = r * g2wv, sh = g2bv - mu * sc;
                GN_STORE(hp2, a0, 0) GN_STORE(hp2, a1, 1)
                GN_STORE(hp2, a2, 2) GN_STORE(hp2, a3, 3)
            }
            __syncthreads();   // B2

            {
                f32x4 a0, a1, a2, a3;
                CONV_MFMA(hp2, w2r)

                RK4_REG(a0, zr0, za0, ur0) RK4_REG(a1, zr1, za1, ur1)
                RK4_REG(a2, zr2, za2, ur2) RK4_REG(a3, zr3, za3, ur3)
                if (e == 3) {
                    zr0 = za0; zr1 = za1; zr2 = za2; zr3 = za3;
                    ur0 = zr0; ur1 = zr1; ur2 = zr2; ur3 = zr3;
                }
            }
        }
    }

    {
        float s = 0.f, s2 = 0.f;
        GN_ACCUM(zr0, 0) GN_ACCUM(zr1, 1) GN_ACCUM(zr2, 2) GN_ACCUM(zr3, 3)
        s += __shfl_xor(s, 16); s2 += __shfl_xor(s2, 16);
        s += __shfl_xor(s, 32); s2 += __shfl_xor(s2, 32);
        s += __shfl_xor(s, 1);  s2 += __shfl_xor(s2, 1);
        float mu = s * (1.f / 98.f);
        float r = rsqrtf(s2 * (1.f / 98.f) - mu * mu + 1e-5f);
        float sc = r * fgw[co], sh = fgb[co] - mu * sc;
        float ps = 0.f;
#pragma unroll
        for (int mm = 0; mm < 4; mm++) {
            f32x4 zz = (mm == 0) ? zr0 : (mm == 1) ? zr1 : (mm == 2) ? zr2 : zr3;
#pragma unroll
            for (int j = 0; j < 4; j++) {
                int p_ = mm * 16 + q * 4 + j;
                if (PVALID(p_)) ps += fmaxf(zz[j] * sc + sh, 0.f);
            }
        }
        ps += __shfl_xor(ps, 16);
        ps += __shfl_xor(ps, 32);
        if (q == 0) pooled[co] = ps * (1.f / 49.f);
    }
    __syncthreads();
    if (t < 10) {
        float a = fcb[t];
#pragma unroll
        for (int k = 0; k < 64; k++) a += pooled[k] * fcw[t * 64 + k];
        out[(size_t)n * 10 + t] = a;
    }
}

static inline int nblk(long long total) { return (int)((total + TPB - 1) / TPB); }

extern "C" void kernel_launch(void* const* d_in, const int* in_sizes, int n_in,
                              void* d_out, int out_size, void* d_ws, size_t ws_size,
                              hipStream_t stream) {
    const float* x       = (const float*)d_in[0];
    const float* conv1_w = (const float*)d_in[1];
    const float* conv1_b = (const float*)d_in[2];
    const float* r1_g1w  = (const float*)d_in[3];
    const float* r1_g1b  = (const float*)d_in[4];
    const float* r1_c1w  = (const float*)d_in[5];
    const float* r1_g2w  = (const float*)d_in[6];
    const float* r1_g2b  = (const float*)d_in[7];
    const float* r1_c2w  = (const float*)d_in[8];
    const float* r1_dw   = (const float*)d_in[9];
    const float* r2_g1w  = (const float*)d_in[10];
    const float* r2_g1b  = (const float*)d_in[11];
    const float* r2_c1w  = (const float*)d_in[12];
    const float* r2_g2w  = (const float*)d_in[13];
    const float* r2_g2b  = (const float*)d_in[14];
    const float* r2_c2w  = (const float*)d_in[15];
    const float* r2_dw   = (const float*)d_in[16];
    const float* o_g1w   = (const float*)d_in[17];
    const float* o_g1b   = (const float*)d_in[18];
    const float* o_c1w   = (const float*)d_in[19];
    const float* o_g2w   = (const float*)d_in[20];
    const float* o_g2b   = (const float*)d_in[21];
    const float* o_c2w   = (const float*)d_in[22];
    const float* fin_gw  = (const float*)d_in[23];
    const float* fin_gb  = (const float*)d_in[24];
    const float* fc_w    = (const float*)d_in[25];
    const float* fc_b    = (const float*)d_in[26];
    float* out = (float*)d_out;

    const long long SZ26 = 512LL * 64 * 26 * 26;
    const long long SZ13 = 512LL * 64 * 13 * 13;
    const long long SZ7  = 512LL * 64 * 7 * 7;
    const long long WBS  = 9 * 2 * 4 * 64 * 8;
    const long long WBS1 = 2 * 4 * 64 * 8;

    unsigned short* B26 = (unsigned short*)d_ws;
    unsigned short* A13 = B26 + SZ26;
    unsigned short* B13 = A13 + SZ13;
    unsigned short* U7  = B13 + SZ13;
    float* Z7   = (float*)(U7 + SZ7 + (SZ7 & 1));
    float* MEAN = Z7 + SZ7;
    float* RSTD = MEAN + 512 * 32;
    unsigned short* WTAB  = (unsigned short*)(RSTD + 512 * 32);
    unsigned short* WB1h  = WTAB;
    unsigned short* WB2h  = WTAB + WBS;
    unsigned short* WB13h = WTAB + 2 * WBS;
    unsigned short* WR2h  = WTAB + 3 * WBS;
    unsigned short* WR11h = WTAB + 4 * WBS;
    unsigned short* WR21h = WTAB + 5 * WBS;
    unsigned short* WD1h  = WTAB + 6 * WBS;
    unsigned short* WD2h  = WTAB + 6 * WBS + WBS1;

    wsplit_all_k<<<nblk(6 * WBS + 2 * WBS1), TPB, 0, stream>>>(
        o_c1w, o_c2w, r1_c2w, r2_c2w, r1_c1w, r2_c1w, r1_dw, r2_dw, WTAB);

    // ---- conv1 + GN stats fused (block per image) ----
    conv1_stats_k<<<512, 256, 0, stream>>>(x, conv1_w, conv1_b, B26, MEAN, RSTD);

    // ---- residual block 1: 26x26 -> 13x13 ----
    conv_s2_mfma_k<false, false><<<512 * 4, 256, 0, stream>>>(B26, WR11h, WD1h, A13, B13,
                                                              MEAN, RSTD, r1_g1w, r1_g1b,
                                                              26, 26, 13, 13, 2, 2);
    conv13_mfma_k<<<512, 256, 0, stream>>>(A13, WB13h, B13, r1_g2w, r1_g2b);

    // ---- residual block 2: 13x13 -> 7x7 ----
    conv_s2_mfma_k<true, true><<<512, 256, 0, stream>>>(B13, WR21h, WD2h, U7, Z7,
                                                        nullptr, nullptr, r2_g1w, r2_g1b,
                                                        13, 13, 7, 7, 1, 1);

    // ---- fused: GN + r2_c2 conv + skip + ODE RK4 + final GN + pool + FC ----
    ode_mfma_k<<<512, 256, 0, stream>>>(U7, Z7, r2_g2w, r2_g2b,
                                        WR2h, WB1h, WB2h,
                                        o_g1w, o_g1b, o_g2w, o_g2b,
                                        fin_gw, fin_gb, fc_w, fc_b, out);
}